// Round 2
// baseline (4369.131 us; speedup 1.0000x reference)
//
#include <hip/hip_runtime.h>

#define N_IND 100000
#define N_COM 100000
#define N_TRU 100000
#define NTOT  300000
#define NEDGE 4800000
#define HDIM  64
#define NB    4688          // ceil(300000/64) buckets of 64 nodes

static __device__ __forceinline__ float elem4(const float4 v, int j) {
  return j == 0 ? v.x : j == 1 ? v.y : j == 2 ? v.z : v.w;
}

// ---------------- encoder: out[base+n] = x[n] @ W + b  (thread per node) ----------------
template <int K>
__global__ __launch_bounds__(256) void encode_kernel(
    const float* __restrict__ xin, const float* __restrict__ W,
    const float* __restrict__ b, float* __restrict__ xout, int n, int base) {
  int node = blockIdx.x * 256 + threadIdx.x;
  if (node >= n) return;
  float acc[HDIM];
#pragma unroll
  for (int f = 0; f < HDIM; ++f) acc[f] = b[f];  // uniform -> s_load
  const float4* xv = (const float4*)(xin + (size_t)node * K);
  for (int k4 = 0; k4 < K / 4; ++k4) {
    float4 xk = xv[k4];
#pragma unroll
    for (int j = 0; j < 4; ++j) {
      float xs = elem4(xk, j);
      int k = k4 * 4 + j;
#pragma unroll
      for (int f = 0; f < HDIM; ++f) acc[f] += xs * W[k * HDIM + f];  // uniform W -> s_load
    }
  }
  float4* ov = (float4*)(xout + (size_t)(base + node) * HDIM);
#pragma unroll
  for (int i = 0; i < HDIM / 4; ++i) {
    float4 o;
    o.x = acc[4 * i + 0]; o.y = acc[4 * i + 1]; o.z = acc[4 * i + 2]; o.w = acc[4 * i + 3];
    ov[i] = o;
  }
}

// ---------------- bucket histogram ----------------
__global__ __launch_bounds__(256) void bucket_hist_kernel(const int* __restrict__ dst,
                                                          int* __restrict__ bhist, int e) {
  int i = blockIdx.x * 256 + threadIdx.x;
  if (i < e) atomicAdd(&bhist[dst[i] >> 6], 1);
}

// ---------------- one-block exclusive scan of NB bucket counts ----------------
__global__ __launch_bounds__(1024) void bucket_scan_kernel(const int* __restrict__ bhist,
                                                           int* __restrict__ boff,
                                                           int* __restrict__ bcur) {
  __shared__ int part[1024];
  int t = threadIdx.x;
  int local[5];
  int s = 0;
#pragma unroll
  for (int j = 0; j < 5; ++j) {
    int i = t * 5 + j;
    int v = (i < NB) ? bhist[i] : 0;
    local[j] = s;
    s += v;
  }
  part[t] = s;
  __syncthreads();
  for (int o = 1; o < 1024; o <<= 1) {
    int y = (t >= o) ? part[t - o] : 0;
    __syncthreads();
    part[t] += y;
    __syncthreads();
  }
  int pre = (t == 0) ? 0 : part[t - 1];
#pragma unroll
  for (int j = 0; j < 5; ++j) {
    int i = t * 5 + j;
    if (i < NB) {
      int o = pre + local[j];
      boff[i] = o;
      bcur[i] = o;
    }
  }
}

// ---------------- scatter packed edges into bucket-contiguous array ----------------
// packed word = (src << 6) | (dst & 63); src < 2^19 so this fits in 25 bits.
__global__ __launch_bounds__(256) void scatter_kernel(const int* __restrict__ src,
                                                      const int* __restrict__ dst,
                                                      int* __restrict__ bcur,
                                                      unsigned* __restrict__ packed, int e) {
  int i = blockIdx.x * 256 + threadIdx.x;
  if (i < e) {
    int s = src[i];
    int d = dst[i];
    int b = d >> 6;
    int p = atomicAdd(&bcur[b], 1);
    packed[p] = ((unsigned)s << 6) | (unsigned)(d & 63);
  }
}

// ---------------- fused aggregate: one block per bucket, 64x64 LDS tile ----------------
__global__ __launch_bounds__(256) void agg_fused_kernel(
    const float* __restrict__ x, const unsigned* __restrict__ packed,
    const int* __restrict__ boff, const int* __restrict__ bhist,
    float* __restrict__ mean) {
  __shared__ float acc[64 * 64];       // 16 KB: acc[dst_local][feat]
  __shared__ unsigned plist[256];
  __shared__ int degs[64];
  int b = blockIdx.x;
  int tid = threadIdx.x;
  for (int i = tid; i < 64 * 64; i += 256) acc[i] = 0.f;
  if (tid < 64) degs[tid] = 0;
  int base = boff[b];
  int cnt = bhist[b];
  const float4* xv = (const float4*)x;
  int lane = tid & 15;
  int sub = tid >> 4;
  for (int t0 = 0; t0 < cnt; t0 += 256) {
    int m = min(256, cnt - t0);
    __syncthreads();  // also covers initial zeroing on first iteration
    if (tid < m) {
      unsigned pr = packed[base + t0 + tid];
      plist[tid] = pr;
      atomicAdd(&degs[pr & 63u], 1);
    }
    __syncthreads();
    for (int e = sub; e < m; e += 16) {
      unsigned pr = plist[e];
      int srcn = (int)(pr >> 6);
      int dl = (int)(pr & 63u);
      float4 v = xv[(size_t)srcn * 16 + lane];
      float* ap = &acc[dl * 64 + lane * 4];
      unsafeAtomicAdd(ap + 0, v.x);
      unsafeAtomicAdd(ap + 1, v.y);
      unsafeAtomicAdd(ap + 2, v.z);
      unsafeAtomicAdd(ap + 3, v.w);
    }
  }
  __syncthreads();
  int r = tid >> 2;
  int c = tid & 3;
  int node = b * 64 + r;
  if (node < NTOT) {
    float inv = 1.0f / (float)max(degs[r], 1);
    float4* ov = (float4*)(mean + (size_t)node * HDIM + c * 16);
    const float* ap = &acc[r * 64 + c * 16];
#pragma unroll
    for (int j = 0; j < 4; ++j) {
      float4 o;
      o.x = ap[4 * j + 0] * inv;
      o.y = ap[4 * j + 1] * inv;
      o.z = ap[4 * j + 2] * inv;
      o.w = ap[4 * j + 3] * inv;
      ov[j] = o;
    }
  }
}

// ---------------- combine: out = relu(mean@Wl + x@Wr + b)  (thread per node) ----------------
__global__ __launch_bounds__(256) void combine_kernel(
    const float* __restrict__ mean, const float* __restrict__ x,
    const float* __restrict__ Wl, const float* __restrict__ Wr,
    const float* __restrict__ bb, float* __restrict__ out, int n, int do_relu) {
  int node = blockIdx.x * 256 + threadIdx.x;
  if (node >= n) return;
  float acc[HDIM];
#pragma unroll
  for (int f = 0; f < HDIM; ++f) acc[f] = bb[f];
  const float4* mv = (const float4*)(mean + (size_t)node * HDIM);
  const float4* xv = (const float4*)(x + (size_t)node * HDIM);
  for (int k4 = 0; k4 < HDIM / 4; ++k4) {
    float4 mk = mv[k4];
    float4 xk = xv[k4];
#pragma unroll
    for (int j = 0; j < 4; ++j) {
      float ms = elem4(mk, j);
      float xs = elem4(xk, j);
      int k = k4 * 4 + j;
#pragma unroll
      for (int f = 0; f < HDIM; ++f)
        acc[f] += ms * Wl[k * HDIM + f] + xs * Wr[k * HDIM + f];  // uniform -> s_load
    }
  }
  float4* ov = (float4*)(out + (size_t)node * HDIM);
#pragma unroll
  for (int i = 0; i < HDIM / 4; ++i) {
    float4 o;
    o.x = acc[4 * i + 0]; o.y = acc[4 * i + 1]; o.z = acc[4 * i + 2]; o.w = acc[4 * i + 3];
    if (do_relu) {
      o.x = fmaxf(o.x, 0.f); o.y = fmaxf(o.y, 0.f);
      o.z = fmaxf(o.z, 0.f); o.w = fmaxf(o.w, 0.f);
    }
    ov[i] = o;
  }
}

// ---------------- classifier: out = relu(x@Wc1+bc1)@Wc2 + bc2 ----------------
__global__ __launch_bounds__(256) void classifier_kernel(
    const float* __restrict__ x, const float* __restrict__ W1, const float* __restrict__ b1,
    const float* __restrict__ W2, const float* __restrict__ b2,
    float* __restrict__ out, int n) {
  int node = blockIdx.x * 256 + threadIdx.x;
  if (node >= n) return;
  float h[32];
#pragma unroll
  for (int f = 0; f < 32; ++f) h[f] = b1[f];
  const float4* xv = (const float4*)(x + (size_t)node * HDIM);
  for (int k4 = 0; k4 < HDIM / 4; ++k4) {
    float4 xk = xv[k4];
#pragma unroll
    for (int j = 0; j < 4; ++j) {
      float xs = elem4(xk, j);
      int k = k4 * 4 + j;
#pragma unroll
      for (int f = 0; f < 32; ++f) h[f] += xs * W1[k * 32 + f];
    }
  }
  float o0 = b2[0], o1 = b2[1];
#pragma unroll
  for (int f = 0; f < 32; ++f) {
    float hv = fmaxf(h[f], 0.f);
    o0 += hv * W2[f * 2 + 0];
    o1 += hv * W2[f * 2 + 1];
  }
  float2 o;
  o.x = o0; o.y = o1;
  *(float2*)(out + (size_t)node * 2) = o;
}

extern "C" void kernel_launch(void* const* d_in, const int* in_sizes, int n_in,
                              void* d_out, int out_size, void* d_ws, size_t ws_size,
                              hipStream_t stream) {
  const float* x_ind = (const float*)d_in[0];
  const float* x_com = (const float*)d_in[1];
  const float* x_tru = (const float*)d_in[2];
  const int*   ei    = (const int*)d_in[3];
  const float* W_ind = (const float*)d_in[4];
  const float* b_ind = (const float*)d_in[5];
  const float* W_com = (const float*)d_in[6];
  const float* b_com = (const float*)d_in[7];
  const float* W_tru = (const float*)d_in[8];
  const float* b_tru = (const float*)d_in[9];
  const float* W1l = (const float*)d_in[10];
  const float* W1r = (const float*)d_in[11];
  const float* b1  = (const float*)d_in[12];
  const float* W2l = (const float*)d_in[13];
  const float* W2r = (const float*)d_in[14];
  const float* b2  = (const float*)d_in[15];
  const float* Wc1 = (const float*)d_in[16];
  const float* bc1 = (const float*)d_in[17];
  const float* Wc2 = (const float*)d_in[18];
  const float* bc2 = (const float*)d_in[19];

  const int* srcp = ei;           // edge_index[0]
  const int* dstp = ei + NEDGE;   // edge_index[1]

  // workspace layout (~250 MB)
  size_t fcount = (size_t)NTOT * HDIM;  // 19.2M floats per buffer
  float* x0       = (float*)d_ws;
  float* x1       = x0 + fcount;
  float* mn       = x1 + fcount;
  unsigned* packed = (unsigned*)(mn + fcount);   // NEDGE words
  int* bhist      = (int*)(packed + NEDGE);
  int* boff       = bhist + NB;
  int* bcur       = boff + NB;
  size_t needed = (3 * fcount + (size_t)NEDGE + 3 * (size_t)NB) * 4;
  if (ws_size < needed) return;  // would corrupt; fail visibly instead

  hipMemsetAsync(bhist, 0, (size_t)NB * sizeof(int), stream);

  // encoders
  encode_kernel<32><<<(N_IND + 255) / 256, 256, 0, stream>>>(x_ind, W_ind, b_ind, x0, N_IND, 0);
  encode_kernel<48><<<(N_COM + 255) / 256, 256, 0, stream>>>(x_com, W_com, b_com, x0, N_COM, N_IND);
  encode_kernel<24><<<(N_TRU + 255) / 256, 256, 0, stream>>>(x_tru, W_tru, b_tru, x0, N_TRU, N_IND + N_COM);

  // bucketed edge structure
  bucket_hist_kernel<<<(NEDGE + 255) / 256, 256, 0, stream>>>(dstp, bhist, NEDGE);
  bucket_scan_kernel<<<1, 1024, 0, stream>>>(bhist, boff, bcur);
  scatter_kernel<<<(NEDGE + 255) / 256, 256, 0, stream>>>(srcp, dstp, bcur, packed, NEDGE);

  // SAGE layer 1
  agg_fused_kernel<<<NB, 256, 0, stream>>>(x0, packed, boff, bhist, mn);
  combine_kernel<<<(NTOT + 255) / 256, 256, 0, stream>>>(mn, x0, W1l, W1r, b1, x1, NTOT, 1);

  // SAGE layer 2
  agg_fused_kernel<<<NB, 256, 0, stream>>>(x1, packed, boff, bhist, mn);
  combine_kernel<<<(NTOT + 255) / 256, 256, 0, stream>>>(mn, x1, W2l, W2r, b2, x0, NTOT, 1);

  // classifier
  classifier_kernel<<<(NTOT + 255) / 256, 256, 0, stream>>>(x0, Wc1, bc1, Wc2, bc2,
                                                            (float*)d_out, NTOT);
}

// Round 3
// 1590.494 us; speedup vs baseline: 2.7470x; 2.7470x over previous
//
#include <hip/hip_runtime.h>

#define N_IND 100000
#define N_COM 100000
#define N_TRU 100000
#define NTOT  300000
#define NEDGE 4800000
#define HDIM  64
#define NB    4688          // ceil(300000/64) buckets of 64 nodes

static __device__ __forceinline__ float elem4(const float4 v, int j) {
  return j == 0 ? v.x : j == 1 ? v.y : j == 2 ? v.z : v.w;
}

// ---------------- encoder: out[base+n] = x[n] @ W + b  (thread per node) ----------------
template <int K>
__global__ __launch_bounds__(256) void encode_kernel(
    const float* __restrict__ xin, const float* __restrict__ W,
    const float* __restrict__ b, float* __restrict__ xout, int n, int base) {
  int node = blockIdx.x * 256 + threadIdx.x;
  if (node >= n) return;
  float acc[HDIM];
#pragma unroll
  for (int f = 0; f < HDIM; ++f) acc[f] = b[f];  // uniform -> s_load
  const float4* xv = (const float4*)(xin + (size_t)node * K);
  for (int k4 = 0; k4 < K / 4; ++k4) {
    float4 xk = xv[k4];
#pragma unroll
    for (int j = 0; j < 4; ++j) {
      float xs = elem4(xk, j);
      int k = k4 * 4 + j;
#pragma unroll
      for (int f = 0; f < HDIM; ++f) acc[f] += xs * W[k * HDIM + f];  // uniform W -> s_load
    }
  }
  float4* ov = (float4*)(xout + (size_t)(base + node) * HDIM);
#pragma unroll
  for (int i = 0; i < HDIM / 4; ++i) {
    float4 o;
    o.x = acc[4 * i + 0]; o.y = acc[4 * i + 1]; o.z = acc[4 * i + 2]; o.w = acc[4 * i + 3];
    ov[i] = o;
  }
}

// ---------------- bucket histogram ----------------
__global__ __launch_bounds__(256) void bucket_hist_kernel(const int* __restrict__ dst,
                                                          int* __restrict__ bhist, int e) {
  int i = blockIdx.x * 256 + threadIdx.x;
  if (i < e) atomicAdd(&bhist[dst[i] >> 6], 1);
}

// ---------------- one-block exclusive scan of NB bucket counts ----------------
__global__ __launch_bounds__(1024) void bucket_scan_kernel(const int* __restrict__ bhist,
                                                           int* __restrict__ boff,
                                                           int* __restrict__ bcur) {
  __shared__ int part[1024];
  int t = threadIdx.x;
  int local[5];
  int s = 0;
#pragma unroll
  for (int j = 0; j < 5; ++j) {
    int i = t * 5 + j;
    int v = (i < NB) ? bhist[i] : 0;
    local[j] = s;
    s += v;
  }
  part[t] = s;
  __syncthreads();
  for (int o = 1; o < 1024; o <<= 1) {
    int y = (t >= o) ? part[t - o] : 0;
    __syncthreads();
    part[t] += y;
    __syncthreads();
  }
  int pre = (t == 0) ? 0 : part[t - 1];
#pragma unroll
  for (int j = 0; j < 5; ++j) {
    int i = t * 5 + j;
    if (i < NB) {
      int o = pre + local[j];
      boff[i] = o;
      bcur[i] = o;
    }
  }
}

// ---------------- scatter packed edges into bucket-contiguous array ----------------
// packed word = (src << 6) | (dst & 63); src < 2^19 so this fits in 25 bits.
__global__ __launch_bounds__(256) void scatter_kernel(const int* __restrict__ src,
                                                      const int* __restrict__ dst,
                                                      int* __restrict__ bcur,
                                                      unsigned* __restrict__ packed, int e) {
  int i = blockIdx.x * 256 + threadIdx.x;
  if (i < e) {
    int s = src[i];
    int d = dst[i];
    int b = d >> 6;
    int p = atomicAdd(&bcur[b], 1);
    packed[p] = ((unsigned)s << 6) | (unsigned)(d & 63);
  }
}

// ---------------- per-bucket counting sort: node-grouped CSR + deg/nodeoff ----------------
__global__ __launch_bounds__(256) void sort_bucket_kernel(
    const unsigned* __restrict__ packed, const int* __restrict__ boff,
    const int* __restrict__ bhist, int* __restrict__ eidx,
    int* __restrict__ nodeoff, int* __restrict__ deg) {
  __shared__ int cnts[64];
  __shared__ int offs[64];
  __shared__ int cur[64];
  int b = blockIdx.x;
  int tid = threadIdx.x;
  if (tid < 64) cnts[tid] = 0;
  __syncthreads();
  int base = boff[b];
  int cnt = bhist[b];
  for (int i = tid; i < cnt; i += 256)
    atomicAdd(&cnts[packed[base + i] & 63u], 1);
  __syncthreads();
  if (tid < 64) offs[tid] = cnts[tid];
  __syncthreads();
  for (int o = 1; o < 64; o <<= 1) {
    int y = 0;
    if (tid < 64 && tid >= o) y = offs[tid - o];
    __syncthreads();
    if (tid < 64) offs[tid] += y;
    __syncthreads();
  }
  if (tid < 64) {
    int ex = offs[tid] - cnts[tid];   // exclusive prefix
    cur[tid] = ex;
    int node = b * 64 + tid;
    if (node < NTOT) {
      deg[node] = cnts[tid];
      nodeoff[node] = base + ex;
    }
  }
  __syncthreads();
  for (int i = tid; i < cnt; i += 256) {
    unsigned pr = packed[base + i];
    int dl = (int)(pr & 63u);
    int r = atomicAdd(&cur[dl], 1);
    eidx[base + r] = (int)(pr >> 6);   // bucket-local write region (~4 KB)
  }
}

// ---------------- mean aggregation: 16 lanes per node, float4 per lane ----------------
__global__ __launch_bounds__(256) void aggregate_kernel(
    const float* __restrict__ x, const int* __restrict__ off, const int* __restrict__ deg,
    const int* __restrict__ eidx, float* __restrict__ mean, int n) {
  int tid = blockIdx.x * 256 + threadIdx.x;
  int node = tid >> 4;
  int lane = tid & 15;
  if (node >= n) return;
  int start = off[node];
  int d = deg[node];
  float4 acc = make_float4(0.f, 0.f, 0.f, 0.f);
  const float4* xv = (const float4*)x;
  for (int i = 0; i < d; ++i) {
    int s = eidx[start + i];
    float4 v = xv[(size_t)s * 16 + lane];
    acc.x += v.x; acc.y += v.y; acc.z += v.z; acc.w += v.w;
  }
  float inv = 1.0f / (float)(d > 0 ? d : 1);
  acc.x *= inv; acc.y *= inv; acc.z *= inv; acc.w *= inv;
  ((float4*)mean)[(size_t)node * 16 + lane] = acc;
}

// ---------------- combine: out = relu(mean@Wl + x@Wr + b)  (thread per node) ----------------
__global__ __launch_bounds__(256) void combine_kernel(
    const float* __restrict__ mean, const float* __restrict__ x,
    const float* __restrict__ Wl, const float* __restrict__ Wr,
    const float* __restrict__ bb, float* __restrict__ out, int n, int do_relu) {
  int node = blockIdx.x * 256 + threadIdx.x;
  if (node >= n) return;
  float acc[HDIM];
#pragma unroll
  for (int f = 0; f < HDIM; ++f) acc[f] = bb[f];
  const float4* mv = (const float4*)(mean + (size_t)node * HDIM);
  const float4* xv = (const float4*)(x + (size_t)node * HDIM);
  for (int k4 = 0; k4 < HDIM / 4; ++k4) {
    float4 mk = mv[k4];
    float4 xk = xv[k4];
#pragma unroll
    for (int j = 0; j < 4; ++j) {
      float ms = elem4(mk, j);
      float xs = elem4(xk, j);
      int k = k4 * 4 + j;
#pragma unroll
      for (int f = 0; f < HDIM; ++f)
        acc[f] += ms * Wl[k * HDIM + f] + xs * Wr[k * HDIM + f];  // uniform -> s_load
    }
  }
  float4* ov = (float4*)(out + (size_t)node * HDIM);
#pragma unroll
  for (int i = 0; i < HDIM / 4; ++i) {
    float4 o;
    o.x = acc[4 * i + 0]; o.y = acc[4 * i + 1]; o.z = acc[4 * i + 2]; o.w = acc[4 * i + 3];
    if (do_relu) {
      o.x = fmaxf(o.x, 0.f); o.y = fmaxf(o.y, 0.f);
      o.z = fmaxf(o.z, 0.f); o.w = fmaxf(o.w, 0.f);
    }
    ov[i] = o;
  }
}

// ---------------- classifier: out = relu(x@Wc1+bc1)@Wc2 + bc2 ----------------
__global__ __launch_bounds__(256) void classifier_kernel(
    const float* __restrict__ x, const float* __restrict__ W1, const float* __restrict__ b1,
    const float* __restrict__ W2, const float* __restrict__ b2,
    float* __restrict__ out, int n) {
  int node = blockIdx.x * 256 + threadIdx.x;
  if (node >= n) return;
  float h[32];
#pragma unroll
  for (int f = 0; f < 32; ++f) h[f] = b1[f];
  const float4* xv = (const float4*)(x + (size_t)node * HDIM);
  for (int k4 = 0; k4 < HDIM / 4; ++k4) {
    float4 xk = xv[k4];
#pragma unroll
    for (int j = 0; j < 4; ++j) {
      float xs = elem4(xk, j);
      int k = k4 * 4 + j;
#pragma unroll
      for (int f = 0; f < 32; ++f) h[f] += xs * W1[k * 32 + f];
    }
  }
  float o0 = b2[0], o1 = b2[1];
#pragma unroll
  for (int f = 0; f < 32; ++f) {
    float hv = fmaxf(h[f], 0.f);
    o0 += hv * W2[f * 2 + 0];
    o1 += hv * W2[f * 2 + 1];
  }
  float2 o;
  o.x = o0; o.y = o1;
  *(float2*)(out + (size_t)node * 2) = o;
}

extern "C" void kernel_launch(void* const* d_in, const int* in_sizes, int n_in,
                              void* d_out, int out_size, void* d_ws, size_t ws_size,
                              hipStream_t stream) {
  const float* x_ind = (const float*)d_in[0];
  const float* x_com = (const float*)d_in[1];
  const float* x_tru = (const float*)d_in[2];
  const int*   ei    = (const int*)d_in[3];
  const float* W_ind = (const float*)d_in[4];
  const float* b_ind = (const float*)d_in[5];
  const float* W_com = (const float*)d_in[6];
  const float* b_com = (const float*)d_in[7];
  const float* W_tru = (const float*)d_in[8];
  const float* b_tru = (const float*)d_in[9];
  const float* W1l = (const float*)d_in[10];
  const float* W1r = (const float*)d_in[11];
  const float* b1  = (const float*)d_in[12];
  const float* W2l = (const float*)d_in[13];
  const float* W2r = (const float*)d_in[14];
  const float* b2  = (const float*)d_in[15];
  const float* Wc1 = (const float*)d_in[16];
  const float* bc1 = (const float*)d_in[17];
  const float* Wc2 = (const float*)d_in[18];
  const float* bc2 = (const float*)d_in[19];

  const int* srcp = ei;           // edge_index[0]
  const int* dstp = ei + NEDGE;   // edge_index[1]

  // workspace layout (~252 MB)
  size_t fcount = (size_t)NTOT * HDIM;  // 19.2M floats per buffer
  float* x0 = (float*)d_ws;
  float* x1 = x0 + fcount;
  float* mn = x1 + fcount;
  unsigned* packed = (unsigned*)mn;      // ALIAS: packed is dead before mn is written
  int* eidx    = (int*)(mn + fcount);
  int* nodeoff = eidx + NEDGE;
  int* deg     = nodeoff + NTOT;
  int* bhist   = deg + NTOT;
  int* boff    = bhist + NB;
  int* bcur    = boff + NB;
  size_t needed = (3 * fcount + (size_t)NEDGE + 2 * (size_t)NTOT + 3 * (size_t)NB) * 4;
  if (ws_size < needed) return;  // would corrupt; fail visibly instead

  hipMemsetAsync(bhist, 0, (size_t)NB * sizeof(int), stream);

  // encoders (write x0; independent of edge pipeline)
  encode_kernel<32><<<(N_IND + 255) / 256, 256, 0, stream>>>(x_ind, W_ind, b_ind, x0, N_IND, 0);
  encode_kernel<48><<<(N_COM + 255) / 256, 256, 0, stream>>>(x_com, W_com, b_com, x0, N_COM, N_IND);
  encode_kernel<24><<<(N_TRU + 255) / 256, 256, 0, stream>>>(x_tru, W_tru, b_tru, x0, N_TRU, N_IND + N_COM);

  // bucketed edge structure -> node-sorted CSR
  bucket_hist_kernel<<<(NEDGE + 255) / 256, 256, 0, stream>>>(dstp, bhist, NEDGE);
  bucket_scan_kernel<<<1, 1024, 0, stream>>>(bhist, boff, bcur);
  scatter_kernel<<<(NEDGE + 255) / 256, 256, 0, stream>>>(srcp, dstp, bcur, packed, NEDGE);
  sort_bucket_kernel<<<NB, 256, 0, stream>>>(packed, boff, bhist, eidx, nodeoff, deg);

  // SAGE layer 1
  aggregate_kernel<<<(NTOT * 16 + 255) / 256, 256, 0, stream>>>(x0, nodeoff, deg, eidx, mn, NTOT);
  combine_kernel<<<(NTOT + 255) / 256, 256, 0, stream>>>(mn, x0, W1l, W1r, b1, x1, NTOT, 1);

  // SAGE layer 2
  aggregate_kernel<<<(NTOT * 16 + 255) / 256, 256, 0, stream>>>(x1, nodeoff, deg, eidx, mn, NTOT);
  combine_kernel<<<(NTOT + 255) / 256, 256, 0, stream>>>(mn, x1, W2l, W2r, b2, x0, NTOT, 1);

  // classifier
  classifier_kernel<<<(NTOT + 255) / 256, 256, 0, stream>>>(x0, Wc1, bc1, Wc2, bc2,
                                                            (float*)d_out, NTOT);
}

// Round 4
// 1193.965 us; speedup vs baseline: 3.6593x; 1.3321x over previous
//
#include <hip/hip_runtime.h>

#define N_IND 100000
#define N_COM 100000
#define N_TRU 100000
#define NTOT  300000
#define NEDGE 4800000
#define HDIM  64
#define CHUNK 8192
#define NCHUNKS 586   // ceil(NEDGE/CHUNK)
#define NCB 293       // ceil(NTOT/1024) coarse buckets of 1024 nodes

static __device__ __forceinline__ float elem4(const float4 v, int j) {
  return j == 0 ? v.x : j == 1 ? v.y : j == 2 ? v.z : v.w;
}

// ---------------- encoder: out[base+n] = x[n] @ W + b  (thread per node) ----------------
template <int K>
__global__ __launch_bounds__(256) void encode_kernel(
    const float* __restrict__ xin, const float* __restrict__ W,
    const float* __restrict__ b, float* __restrict__ xout, int n, int base) {
  int node = blockIdx.x * 256 + threadIdx.x;
  if (node >= n) return;
  float acc[HDIM];
#pragma unroll
  for (int f = 0; f < HDIM; ++f) acc[f] = b[f];  // uniform -> s_load
  const float4* xv = (const float4*)(xin + (size_t)node * K);
  for (int k4 = 0; k4 < K / 4; ++k4) {
    float4 xk = xv[k4];
#pragma unroll
    for (int j = 0; j < 4; ++j) {
      float xs = elem4(xk, j);
      int k = k4 * 4 + j;
#pragma unroll
      for (int f = 0; f < HDIM; ++f) acc[f] += xs * W[k * HDIM + f];  // uniform W -> s_load
    }
  }
  float4* ov = (float4*)(xout + (size_t)(base + node) * HDIM);
#pragma unroll
  for (int i = 0; i < HDIM / 4; ++i) {
    float4 o;
    o.x = acc[4 * i + 0]; o.y = acc[4 * i + 1]; o.z = acc[4 * i + 2]; o.w = acc[4 * i + 3];
    ov[i] = o;
  }
}

// ---------------- coarse histogram: LDS-aggregated, 293 bins ----------------
__global__ __launch_bounds__(256) void coarse_hist_kernel(const int* __restrict__ dst,
                                                          int* __restrict__ chist, int e) {
  __shared__ int h[NCB];
  int tid = threadIdx.x;
  int start = blockIdx.x * CHUNK;
  int len = min(CHUNK, e - start);
  for (int i = tid; i < NCB; i += 256) h[i] = 0;
  __syncthreads();
  for (int i = tid; i < len; i += 256) atomicAdd(&h[dst[start + i] >> 10], 1);
  __syncthreads();
  for (int b = tid; b < NCB; b += 256) {
    int c = h[b];
    if (c > 0) atomicAdd(&chist[b], c);
  }
}

// ---------------- exclusive scan of 293 coarse counts ----------------
__global__ __launch_bounds__(512) void coarse_scan_kernel(const int* __restrict__ chist,
                                                          int* __restrict__ cbase,
                                                          int* __restrict__ ccur) {
  __shared__ int sv[512];
  int t = threadIdx.x;
  sv[t] = (t < NCB) ? chist[t] : 0;
  __syncthreads();
  for (int o = 1; o < 512; o <<= 1) {
    int y = (t >= o) ? sv[t - o] : 0;
    __syncthreads();
    sv[t] += y;
    __syncthreads();
  }
  if (t < NCB) {
    int ex = (t == 0) ? 0 : sv[t - 1];
    cbase[t] = ex;
    ccur[t] = ex;
  }
}

// ---------------- coarse scatter: block-aggregated reservation, dense runs ----------------
// packed word = (src << 10) | (dst & 1023); src < 2^19 -> 29 bits.
__global__ __launch_bounds__(256) void coarse_scatter_kernel(
    const int* __restrict__ src, const int* __restrict__ dst,
    int* __restrict__ ccur, unsigned* __restrict__ packed, int e) {
  __shared__ int h[NCB];
  __shared__ int lbase[NCB];
  int tid = threadIdx.x;
  int start = blockIdx.x * CHUNK;
  int len = min(CHUNK, e - start);
  for (int i = tid; i < NCB; i += 256) h[i] = 0;
  __syncthreads();
  for (int i = tid; i < len; i += 256) atomicAdd(&h[dst[start + i] >> 10], 1);
  __syncthreads();
  for (int b = tid; b < NCB; b += 256) {
    int c = h[b];
    lbase[b] = (c > 0) ? atomicAdd(&ccur[b], c) : 0;  // reserve contiguous run
  }
  __syncthreads();
  for (int i = tid; i < NCB; i += 256) h[i] = 0;  // reuse as rank counters
  __syncthreads();
  for (int i = tid; i < len; i += 256) {
    int d = dst[start + i];
    int s = src[start + i];
    int b = d >> 10;
    int r = atomicAdd(&h[b], 1);
    packed[lbase[b] + r] = ((unsigned)s << 10) | (unsigned)(d & 1023);
  }
}

// ---------------- per-coarse-bucket counting sort -> node-grouped CSR ----------------
__global__ __launch_bounds__(256) void sort_coarse_kernel(
    const unsigned* __restrict__ packed, const int* __restrict__ cbase,
    const int* __restrict__ chist, int* __restrict__ eidx,
    int* __restrict__ nodeoff, int* __restrict__ deg) {
  __shared__ int cnts[1024];
  __shared__ int cur[1024];
  __shared__ int part[256];
  int cb = blockIdx.x;
  int tid = threadIdx.x;
  for (int i = tid; i < 1024; i += 256) cnts[i] = 0;
  __syncthreads();
  int base = cbase[cb];
  int cnt = chist[cb];
  for (int i = tid; i < cnt; i += 256)
    atomicAdd(&cnts[packed[base + i] & 1023u], 1);
  __syncthreads();
  int c0 = cnts[4 * tid + 0], c1 = cnts[4 * tid + 1];
  int c2 = cnts[4 * tid + 2], c3 = cnts[4 * tid + 3];
  part[tid] = c0 + c1 + c2 + c3;
  __syncthreads();
  for (int o = 1; o < 256; o <<= 1) {
    int y = (tid >= o) ? part[tid - o] : 0;
    __syncthreads();
    part[tid] += y;
    __syncthreads();
  }
  int pre = (tid == 0) ? 0 : part[tid - 1];
  int e0 = pre, e1 = e0 + c0, e2 = e1 + c1, e3 = e2 + c2;
  cur[4 * tid + 0] = e0; cur[4 * tid + 1] = e1;
  cur[4 * tid + 2] = e2; cur[4 * tid + 3] = e3;
  int nodebase = (cb << 10) + 4 * tid;
  if (nodebase + 0 < NTOT) { deg[nodebase + 0] = c0; nodeoff[nodebase + 0] = base + e0; }
  if (nodebase + 1 < NTOT) { deg[nodebase + 1] = c1; nodeoff[nodebase + 1] = base + e1; }
  if (nodebase + 2 < NTOT) { deg[nodebase + 2] = c2; nodeoff[nodebase + 2] = base + e2; }
  if (nodebase + 3 < NTOT) { deg[nodebase + 3] = c3; nodeoff[nodebase + 3] = base + e3; }
  __syncthreads();
  for (int i = tid; i < cnt; i += 256) {
    unsigned pr = packed[base + i];
    int dl = (int)(pr & 1023u);
    int r = atomicAdd(&cur[dl], 1);
    eidx[base + r] = (int)(pr >> 10);  // 64 KB region exclusive to this block
  }
}

// ---------------- mean aggregation: 16 lanes per node, float4 per lane ----------------
__global__ __launch_bounds__(256) void aggregate_kernel(
    const float* __restrict__ x, const int* __restrict__ off, const int* __restrict__ deg,
    const int* __restrict__ eidx, float* __restrict__ mean, int n) {
  int tid = blockIdx.x * 256 + threadIdx.x;
  int node = tid >> 4;
  int lane = tid & 15;
  if (node >= n) return;
  int start = off[node];
  int d = deg[node];
  float4 acc = make_float4(0.f, 0.f, 0.f, 0.f);
  const float4* xv = (const float4*)x;
  for (int i = 0; i < d; ++i) {
    int s = eidx[start + i];
    float4 v = xv[(size_t)s * 16 + lane];
    acc.x += v.x; acc.y += v.y; acc.z += v.z; acc.w += v.w;
  }
  float inv = 1.0f / (float)(d > 0 ? d : 1);
  acc.x *= inv; acc.y *= inv; acc.z *= inv; acc.w *= inv;
  ((float4*)mean)[(size_t)node * 16 + lane] = acc;
}

// ---------------- combine: out = relu(mean@Wl + x@Wr + b)  (thread per node) ----------------
__global__ __launch_bounds__(256) void combine_kernel(
    const float* __restrict__ mean, const float* __restrict__ x,
    const float* __restrict__ Wl, const float* __restrict__ Wr,
    const float* __restrict__ bb, float* __restrict__ out, int n, int do_relu) {
  int node = blockIdx.x * 256 + threadIdx.x;
  if (node >= n) return;
  float acc[HDIM];
#pragma unroll
  for (int f = 0; f < HDIM; ++f) acc[f] = bb[f];
  const float4* mv = (const float4*)(mean + (size_t)node * HDIM);
  const float4* xv = (const float4*)(x + (size_t)node * HDIM);
  for (int k4 = 0; k4 < HDIM / 4; ++k4) {
    float4 mk = mv[k4];
    float4 xk = xv[k4];
#pragma unroll
    for (int j = 0; j < 4; ++j) {
      float ms = elem4(mk, j);
      float xs = elem4(xk, j);
      int k = k4 * 4 + j;
#pragma unroll
      for (int f = 0; f < HDIM; ++f)
        acc[f] += ms * Wl[k * HDIM + f] + xs * Wr[k * HDIM + f];  // uniform -> s_load
    }
  }
  float4* ov = (float4*)(out + (size_t)node * HDIM);
#pragma unroll
  for (int i = 0; i < HDIM / 4; ++i) {
    float4 o;
    o.x = acc[4 * i + 0]; o.y = acc[4 * i + 1]; o.z = acc[4 * i + 2]; o.w = acc[4 * i + 3];
    if (do_relu) {
      o.x = fmaxf(o.x, 0.f); o.y = fmaxf(o.y, 0.f);
      o.z = fmaxf(o.z, 0.f); o.w = fmaxf(o.w, 0.f);
    }
    ov[i] = o;
  }
}

// ---------------- classifier: out = relu(x@Wc1+bc1)@Wc2 + bc2 ----------------
__global__ __launch_bounds__(256) void classifier_kernel(
    const float* __restrict__ x, const float* __restrict__ W1, const float* __restrict__ b1,
    const float* __restrict__ W2, const float* __restrict__ b2,
    float* __restrict__ out, int n) {
  int node = blockIdx.x * 256 + threadIdx.x;
  if (node >= n) return;
  float h[32];
#pragma unroll
  for (int f = 0; f < 32; ++f) h[f] = b1[f];
  const float4* xv = (const float4*)(x + (size_t)node * HDIM);
  for (int k4 = 0; k4 < HDIM / 4; ++k4) {
    float4 xk = xv[k4];
#pragma unroll
    for (int j = 0; j < 4; ++j) {
      float xs = elem4(xk, j);
      int k = k4 * 4 + j;
#pragma unroll
      for (int f = 0; f < 32; ++f) h[f] += xs * W1[k * 32 + f];
    }
  }
  float o0 = b2[0], o1 = b2[1];
#pragma unroll
  for (int f = 0; f < 32; ++f) {
    float hv = fmaxf(h[f], 0.f);
    o0 += hv * W2[f * 2 + 0];
    o1 += hv * W2[f * 2 + 1];
  }
  float2 o;
  o.x = o0; o.y = o1;
  *(float2*)(out + (size_t)node * 2) = o;
}

extern "C" void kernel_launch(void* const* d_in, const int* in_sizes, int n_in,
                              void* d_out, int out_size, void* d_ws, size_t ws_size,
                              hipStream_t stream) {
  const float* x_ind = (const float*)d_in[0];
  const float* x_com = (const float*)d_in[1];
  const float* x_tru = (const float*)d_in[2];
  const int*   ei    = (const int*)d_in[3];
  const float* W_ind = (const float*)d_in[4];
  const float* b_ind = (const float*)d_in[5];
  const float* W_com = (const float*)d_in[6];
  const float* b_com = (const float*)d_in[7];
  const float* W_tru = (const float*)d_in[8];
  const float* b_tru = (const float*)d_in[9];
  const float* W1l = (const float*)d_in[10];
  const float* W1r = (const float*)d_in[11];
  const float* b1  = (const float*)d_in[12];
  const float* W2l = (const float*)d_in[13];
  const float* W2r = (const float*)d_in[14];
  const float* b2  = (const float*)d_in[15];
  const float* Wc1 = (const float*)d_in[16];
  const float* bc1 = (const float*)d_in[17];
  const float* Wc2 = (const float*)d_in[18];
  const float* bc2 = (const float*)d_in[19];

  const int* srcp = ei;           // edge_index[0]
  const int* dstp = ei + NEDGE;   // edge_index[1]

  // workspace layout (~252 MB)
  size_t fcount = (size_t)NTOT * HDIM;  // 19.2M floats per buffer
  float* x0 = (float*)d_ws;
  float* x1 = x0 + fcount;
  float* mn = x1 + fcount;
  unsigned* packed = (unsigned*)mn;      // ALIAS: packed dead before mn first written
  int* eidx    = (int*)(mn + fcount);
  int* nodeoff = eidx + NEDGE;
  int* deg     = nodeoff + NTOT;
  int* chist   = deg + NTOT;
  int* cbase   = chist + NCB;
  int* ccur    = cbase + NCB;
  size_t needed = (3 * fcount + (size_t)NEDGE + 2 * (size_t)NTOT + 3 * (size_t)NCB) * 4;
  if (ws_size < needed) return;  // would corrupt; fail visibly instead

  hipMemsetAsync(chist, 0, (size_t)NCB * sizeof(int), stream);

  // encoders (write x0; independent of edge pipeline)
  encode_kernel<32><<<(N_IND + 255) / 256, 256, 0, stream>>>(x_ind, W_ind, b_ind, x0, N_IND, 0);
  encode_kernel<48><<<(N_COM + 255) / 256, 256, 0, stream>>>(x_com, W_com, b_com, x0, N_COM, N_IND);
  encode_kernel<24><<<(N_TRU + 255) / 256, 256, 0, stream>>>(x_tru, W_tru, b_tru, x0, N_TRU, N_IND + N_COM);

  // coarse partition -> per-coarse-bucket counting sort -> node-grouped CSR
  coarse_hist_kernel<<<NCHUNKS, 256, 0, stream>>>(dstp, chist, NEDGE);
  coarse_scan_kernel<<<1, 512, 0, stream>>>(chist, cbase, ccur);
  coarse_scatter_kernel<<<NCHUNKS, 256, 0, stream>>>(srcp, dstp, ccur, packed, NEDGE);
  sort_coarse_kernel<<<NCB, 256, 0, stream>>>(packed, cbase, chist, eidx, nodeoff, deg);

  // SAGE layer 1
  aggregate_kernel<<<(NTOT * 16 + 255) / 256, 256, 0, stream>>>(x0, nodeoff, deg, eidx, mn, NTOT);
  combine_kernel<<<(NTOT + 255) / 256, 256, 0, stream>>>(mn, x0, W1l, W1r, b1, x1, NTOT, 1);

  // SAGE layer 2
  aggregate_kernel<<<(NTOT * 16 + 255) / 256, 256, 0, stream>>>(x1, nodeoff, deg, eidx, mn, NTOT);
  combine_kernel<<<(NTOT + 255) / 256, 256, 0, stream>>>(mn, x1, W2l, W2r, b2, x0, NTOT, 1);

  // classifier
  classifier_kernel<<<(NTOT + 255) / 256, 256, 0, stream>>>(x0, Wc1, bc1, Wc2, bc2,
                                                            (float*)d_out, NTOT);
}

// Round 5
// 1163.776 us; speedup vs baseline: 3.7543x; 1.0259x over previous
//
#include <hip/hip_runtime.h>

#define N_IND 100000
#define N_COM 100000
#define N_TRU 100000
#define NTOT  300000
#define NEDGE 4800000
#define HDIM  64
#define CHUNK 8192
#define NCHUNKS 586   // ceil(NEDGE/CHUNK)
#define NCB 293       // ceil(NTOT/1024) coarse buckets of 1024 nodes

static __device__ __forceinline__ float elem4(const float4 v, int j) {
  return j == 0 ? v.x : j == 1 ? v.y : j == 2 ? v.z : v.w;
}

// ---------------- encoder: out[base+n] = x[n] @ W + b  (thread per node) ----------------
template <int K>
__global__ __launch_bounds__(256, 2) void encode_kernel(
    const float* __restrict__ xin, const float* __restrict__ W,
    const float* __restrict__ b, float* __restrict__ xout, int n, int base) {
  int node = blockIdx.x * 256 + threadIdx.x;
  if (node >= n) return;
  // burst-load the full input row first (lines fully consumed while L1-resident)
  float4 row[K / 4];
  const float4* xv = (const float4*)(xin + (size_t)node * K);
#pragma unroll
  for (int i = 0; i < K / 4; ++i) row[i] = xv[i];
  float acc[HDIM];
#pragma unroll
  for (int f = 0; f < HDIM; ++f) acc[f] = b[f];  // uniform -> s_load
#pragma unroll
  for (int k4 = 0; k4 < K / 4; ++k4) {
#pragma unroll
    for (int j = 0; j < 4; ++j) {
      float xs = elem4(row[k4], j);
      int k = k4 * 4 + j;
#pragma unroll
      for (int f = 0; f < HDIM; ++f) acc[f] += xs * W[k * HDIM + f];  // uniform W -> s_load
    }
  }
  float4* ov = (float4*)(xout + (size_t)(base + node) * HDIM);
#pragma unroll
  for (int i = 0; i < HDIM / 4; ++i) {
    float4 o;
    o.x = acc[4 * i + 0]; o.y = acc[4 * i + 1]; o.z = acc[4 * i + 2]; o.w = acc[4 * i + 3];
    ov[i] = o;
  }
}

// ---------------- coarse histogram: LDS-aggregated, 293 bins ----------------
__global__ __launch_bounds__(256) void coarse_hist_kernel(const int* __restrict__ dst,
                                                          int* __restrict__ chist, int e) {
  __shared__ int h[NCB];
  int tid = threadIdx.x;
  int start = blockIdx.x * CHUNK;
  int len = min(CHUNK, e - start);
  for (int i = tid; i < NCB; i += 256) h[i] = 0;
  __syncthreads();
  for (int i = tid; i < len; i += 256) atomicAdd(&h[dst[start + i] >> 10], 1);
  __syncthreads();
  for (int b = tid; b < NCB; b += 256) {
    int c = h[b];
    if (c > 0) atomicAdd(&chist[b], c);
  }
}

// ---------------- exclusive scan of 293 coarse counts ----------------
__global__ __launch_bounds__(512) void coarse_scan_kernel(const int* __restrict__ chist,
                                                          int* __restrict__ cbase,
                                                          int* __restrict__ ccur) {
  __shared__ int sv[512];
  int t = threadIdx.x;
  sv[t] = (t < NCB) ? chist[t] : 0;
  __syncthreads();
  for (int o = 1; o < 512; o <<= 1) {
    int y = (t >= o) ? sv[t - o] : 0;
    __syncthreads();
    sv[t] += y;
    __syncthreads();
  }
  if (t < NCB) {
    int ex = (t == 0) ? 0 : sv[t - 1];
    cbase[t] = ex;
    ccur[t] = ex;
  }
}

// ---------------- coarse scatter: block-aggregated reservation, dense runs ----------------
// packed word = (src << 10) | (dst & 1023); src < 2^19 -> 29 bits.
__global__ __launch_bounds__(256) void coarse_scatter_kernel(
    const int* __restrict__ src, const int* __restrict__ dst,
    int* __restrict__ ccur, unsigned* __restrict__ packed, int e) {
  __shared__ int h[NCB];
  __shared__ int lbase[NCB];
  int tid = threadIdx.x;
  int start = blockIdx.x * CHUNK;
  int len = min(CHUNK, e - start);
  for (int i = tid; i < NCB; i += 256) h[i] = 0;
  __syncthreads();
  for (int i = tid; i < len; i += 256) atomicAdd(&h[dst[start + i] >> 10], 1);
  __syncthreads();
  for (int b = tid; b < NCB; b += 256) {
    int c = h[b];
    lbase[b] = (c > 0) ? atomicAdd(&ccur[b], c) : 0;  // reserve contiguous run
  }
  __syncthreads();
  for (int i = tid; i < NCB; i += 256) h[i] = 0;  // reuse as rank counters
  __syncthreads();
  for (int i = tid; i < len; i += 256) {
    int d = dst[start + i];
    int s = src[start + i];
    int b = d >> 10;
    int r = atomicAdd(&h[b], 1);
    packed[lbase[b] + r] = ((unsigned)s << 10) | (unsigned)(d & 1023);
  }
}

// ---------------- per-coarse-bucket counting sort -> node-grouped CSR ----------------
__global__ __launch_bounds__(256) void sort_coarse_kernel(
    const unsigned* __restrict__ packed, const int* __restrict__ cbase,
    const int* __restrict__ chist, int* __restrict__ eidx,
    int* __restrict__ nodeoff, int* __restrict__ deg) {
  __shared__ int cnts[1024];
  __shared__ int cur[1024];
  __shared__ int part[256];
  int cb = blockIdx.x;
  int tid = threadIdx.x;
  for (int i = tid; i < 1024; i += 256) cnts[i] = 0;
  __syncthreads();
  int base = cbase[cb];
  int cnt = chist[cb];
  for (int i = tid; i < cnt; i += 256)
    atomicAdd(&cnts[packed[base + i] & 1023u], 1);
  __syncthreads();
  int c0 = cnts[4 * tid + 0], c1 = cnts[4 * tid + 1];
  int c2 = cnts[4 * tid + 2], c3 = cnts[4 * tid + 3];
  part[tid] = c0 + c1 + c2 + c3;
  __syncthreads();
  for (int o = 1; o < 256; o <<= 1) {
    int y = (tid >= o) ? part[tid - o] : 0;
    __syncthreads();
    part[tid] += y;
    __syncthreads();
  }
  int pre = (tid == 0) ? 0 : part[tid - 1];
  int e0 = pre, e1 = e0 + c0, e2 = e1 + c1, e3 = e2 + c2;
  cur[4 * tid + 0] = e0; cur[4 * tid + 1] = e1;
  cur[4 * tid + 2] = e2; cur[4 * tid + 3] = e3;
  int nodebase = (cb << 10) + 4 * tid;
  if (nodebase + 0 < NTOT) { deg[nodebase + 0] = c0; nodeoff[nodebase + 0] = base + e0; }
  if (nodebase + 1 < NTOT) { deg[nodebase + 1] = c1; nodeoff[nodebase + 1] = base + e1; }
  if (nodebase + 2 < NTOT) { deg[nodebase + 2] = c2; nodeoff[nodebase + 2] = base + e2; }
  if (nodebase + 3 < NTOT) { deg[nodebase + 3] = c3; nodeoff[nodebase + 3] = base + e3; }
  __syncthreads();
  for (int i = tid; i < cnt; i += 256) {
    unsigned pr = packed[base + i];
    int dl = (int)(pr & 1023u);
    int r = atomicAdd(&cur[dl], 1);
    eidx[base + r] = (int)(pr >> 10);  // 64 KB region exclusive to this block
  }
}

// ---------------- mean aggregation: 16 lanes per node, float4 per lane ----------------
__global__ __launch_bounds__(256) void aggregate_kernel(
    const float* __restrict__ x, const int* __restrict__ off, const int* __restrict__ deg,
    const int* __restrict__ eidx, float* __restrict__ mean, int n) {
  int tid = blockIdx.x * 256 + threadIdx.x;
  int node = tid >> 4;
  int lane = tid & 15;
  if (node >= n) return;
  int start = off[node];
  int d = deg[node];
  float4 acc = make_float4(0.f, 0.f, 0.f, 0.f);
  const float4* xv = (const float4*)x;
  for (int i = 0; i < d; ++i) {
    int s = eidx[start + i];
    float4 v = xv[(size_t)s * 16 + lane];
    acc.x += v.x; acc.y += v.y; acc.z += v.z; acc.w += v.w;
  }
  float inv = 1.0f / (float)(d > 0 ? d : 1);
  acc.x *= inv; acc.y *= inv; acc.z *= inv; acc.w *= inv;
  ((float4*)mean)[(size_t)node * 16 + lane] = acc;
}

// ---------------- combine: out = relu(mean@Wl + x@Wr + b)  (thread per node) ----------------
__global__ __launch_bounds__(256, 2) void combine_kernel(
    const float* __restrict__ mean, const float* __restrict__ x,
    const float* __restrict__ Wl, const float* __restrict__ Wr,
    const float* __restrict__ bb, float* __restrict__ out, int n) {
  int node = blockIdx.x * 256 + threadIdx.x;
  if (node >= n) return;
  float acc[HDIM];
#pragma unroll
  for (int f = 0; f < HDIM; ++f) acc[f] = bb[f];

  float4 row[16];
  // phase 1: mean @ Wl  (burst-load full row, then FMA from registers)
  const float4* mv = (const float4*)(mean + (size_t)node * HDIM);
#pragma unroll
  for (int i = 0; i < 16; ++i) row[i] = mv[i];
#pragma unroll
  for (int k4 = 0; k4 < 16; ++k4) {
#pragma unroll
    for (int j = 0; j < 4; ++j) {
      float ms = elem4(row[k4], j);
      int k = k4 * 4 + j;
#pragma unroll
      for (int f = 0; f < HDIM; ++f) acc[f] += ms * Wl[k * HDIM + f];  // uniform -> s_load
    }
  }
  // phase 2: x @ Wr
  const float4* xv = (const float4*)(x + (size_t)node * HDIM);
#pragma unroll
  for (int i = 0; i < 16; ++i) row[i] = xv[i];
#pragma unroll
  for (int k4 = 0; k4 < 16; ++k4) {
#pragma unroll
    for (int j = 0; j < 4; ++j) {
      float xs = elem4(row[k4], j);
      int k = k4 * 4 + j;
#pragma unroll
      for (int f = 0; f < HDIM; ++f) acc[f] += xs * Wr[k * HDIM + f];  // uniform -> s_load
    }
  }
  float4* ov = (float4*)(out + (size_t)node * HDIM);
#pragma unroll
  for (int i = 0; i < HDIM / 4; ++i) {
    float4 o;
    o.x = fmaxf(acc[4 * i + 0], 0.f);
    o.y = fmaxf(acc[4 * i + 1], 0.f);
    o.z = fmaxf(acc[4 * i + 2], 0.f);
    o.w = fmaxf(acc[4 * i + 3], 0.f);
    ov[i] = o;
  }
}

// ---------------- classifier: out = relu(x@Wc1+bc1)@Wc2 + bc2 ----------------
__global__ __launch_bounds__(256, 2) void classifier_kernel(
    const float* __restrict__ x, const float* __restrict__ W1, const float* __restrict__ b1,
    const float* __restrict__ W2, const float* __restrict__ b2,
    float* __restrict__ out, int n) {
  int node = blockIdx.x * 256 + threadIdx.x;
  if (node >= n) return;
  float4 row[16];
  const float4* xv = (const float4*)(x + (size_t)node * HDIM);
#pragma unroll
  for (int i = 0; i < 16; ++i) row[i] = xv[i];
  float h[32];
#pragma unroll
  for (int f = 0; f < 32; ++f) h[f] = b1[f];
#pragma unroll
  for (int k4 = 0; k4 < 16; ++k4) {
#pragma unroll
    for (int j = 0; j < 4; ++j) {
      float xs = elem4(row[k4], j);
      int k = k4 * 4 + j;
#pragma unroll
      for (int f = 0; f < 32; ++f) h[f] += xs * W1[k * 32 + f];
    }
  }
  float o0 = b2[0], o1 = b2[1];
#pragma unroll
  for (int f = 0; f < 32; ++f) {
    float hv = fmaxf(h[f], 0.f);
    o0 += hv * W2[f * 2 + 0];
    o1 += hv * W2[f * 2 + 1];
  }
  float2 o;
  o.x = o0; o.y = o1;
  *(float2*)(out + (size_t)node * 2) = o;
}

extern "C" void kernel_launch(void* const* d_in, const int* in_sizes, int n_in,
                              void* d_out, int out_size, void* d_ws, size_t ws_size,
                              hipStream_t stream) {
  const float* x_ind = (const float*)d_in[0];
  const float* x_com = (const float*)d_in[1];
  const float* x_tru = (const float*)d_in[2];
  const int*   ei    = (const int*)d_in[3];
  const float* W_ind = (const float*)d_in[4];
  const float* b_ind = (const float*)d_in[5];
  const float* W_com = (const float*)d_in[6];
  const float* b_com = (const float*)d_in[7];
  const float* W_tru = (const float*)d_in[8];
  const float* b_tru = (const float*)d_in[9];
  const float* W1l = (const float*)d_in[10];
  const float* W1r = (const float*)d_in[11];
  const float* b1  = (const float*)d_in[12];
  const float* W2l = (const float*)d_in[13];
  const float* W2r = (const float*)d_in[14];
  const float* b2  = (const float*)d_in[15];
  const float* Wc1 = (const float*)d_in[16];
  const float* bc1 = (const float*)d_in[17];
  const float* Wc2 = (const float*)d_in[18];
  const float* bc2 = (const float*)d_in[19];

  const int* srcp = ei;           // edge_index[0]
  const int* dstp = ei + NEDGE;   // edge_index[1]

  // workspace layout (~252 MB)
  size_t fcount = (size_t)NTOT * HDIM;  // 19.2M floats per buffer
  float* x0 = (float*)d_ws;
  float* x1 = x0 + fcount;
  float* mn = x1 + fcount;
  unsigned* packed = (unsigned*)mn;      // ALIAS: packed dead before mn first written
  int* eidx    = (int*)(mn + fcount);
  int* nodeoff = eidx + NEDGE;
  int* deg     = nodeoff + NTOT;
  int* chist   = deg + NTOT;
  int* cbase   = chist + NCB;
  int* ccur    = cbase + NCB;
  size_t needed = (3 * fcount + (size_t)NEDGE + 2 * (size_t)NTOT + 3 * (size_t)NCB) * 4;
  if (ws_size < needed) return;  // would corrupt; fail visibly instead

  hipMemsetAsync(chist, 0, (size_t)NCB * sizeof(int), stream);

  // encoders (write x0; independent of edge pipeline)
  encode_kernel<32><<<(N_IND + 255) / 256, 256, 0, stream>>>(x_ind, W_ind, b_ind, x0, N_IND, 0);
  encode_kernel<48><<<(N_COM + 255) / 256, 256, 0, stream>>>(x_com, W_com, b_com, x0, N_COM, N_IND);
  encode_kernel<24><<<(N_TRU + 255) / 256, 256, 0, stream>>>(x_tru, W_tru, b_tru, x0, N_TRU, N_IND + N_COM);

  // coarse partition -> per-coarse-bucket counting sort -> node-grouped CSR
  coarse_hist_kernel<<<NCHUNKS, 256, 0, stream>>>(dstp, chist, NEDGE);
  coarse_scan_kernel<<<1, 512, 0, stream>>>(chist, cbase, ccur);
  coarse_scatter_kernel<<<NCHUNKS, 256, 0, stream>>>(srcp, dstp, ccur, packed, NEDGE);
  sort_coarse_kernel<<<NCB, 256, 0, stream>>>(packed, cbase, chist, eidx, nodeoff, deg);

  // SAGE layer 1
  aggregate_kernel<<<(NTOT * 16 + 255) / 256, 256, 0, stream>>>(x0, nodeoff, deg, eidx, mn, NTOT);
  combine_kernel<<<(NTOT + 255) / 256, 256, 0, stream>>>(mn, x0, W1l, W1r, b1, x1, NTOT);

  // SAGE layer 2
  aggregate_kernel<<<(NTOT * 16 + 255) / 256, 256, 0, stream>>>(x1, nodeoff, deg, eidx, mn, NTOT);
  combine_kernel<<<(NTOT + 255) / 256, 256, 0, stream>>>(mn, x1, W2l, W2r, b2, x0, NTOT);

  // classifier
  classifier_kernel<<<(NTOT + 255) / 256, 256, 0, stream>>>(x0, Wc1, bc1, Wc2, bc2,
                                                            (float*)d_out, NTOT);
}

// Round 6
// 1085.166 us; speedup vs baseline: 4.0262x; 1.0724x over previous
//
#include <hip/hip_runtime.h>

#define N_IND 100000
#define N_COM 100000
#define N_TRU 100000
#define NTOT  300000
#define NEDGE 4800000
#define HDIM  64
#define CHUNK 8192
#define NCHUNKS 586   // ceil(NEDGE/CHUNK)
#define NCB 293       // ceil(NTOT/1024) coarse buckets of 1024 nodes
#define PADW 33       // 32 cols + 1 pad: copy-in/out <=2-way bank alias (free)

static __device__ __forceinline__ float elem4(const float4 v, int j) {
  return j == 0 ? v.x : j == 1 ? v.y : j == 2 ? v.z : v.w;
}

// Coalesced epilogue: stage acc[64] rows through LDS in 2 x 32-col stages so
// every global store instruction writes full 64B lines (fixes 4x write amp).
static __device__ __forceinline__ void store_rows_coalesced(
    float* __restrict__ out, float* __restrict__ st, const float* acc,
    int node0, int rows, int tid, bool active) {
#pragma unroll
  for (int stage = 0; stage < 2; ++stage) {
    __syncthreads();  // protect LDS reuse across stages
    if (active) {
#pragma unroll
      for (int j = 0; j < 32; ++j) st[tid * PADW + j] = acc[stage * 32 + j];
    }
    __syncthreads();
#pragma unroll
    for (int it = 0; it < 8; ++it) {
      int e = it * 256 + tid;   // float4 index within the 256x32 tile
      int r = e >> 3;
      int c = (e & 7) * 4;
      if (r < rows) {
        float4 o;
        o.x = st[r * PADW + c + 0];
        o.y = st[r * PADW + c + 1];
        o.z = st[r * PADW + c + 2];
        o.w = st[r * PADW + c + 3];
        *(float4*)(out + (size_t)(node0 + r) * HDIM + stage * 32 + c) = o;
      }
    }
  }
}

// ---------------- encoder: out[base+n] = x[n] @ W + b ----------------
template <int K>
__global__ __launch_bounds__(256, 2) void encode_kernel(
    const float* __restrict__ xin, const float* __restrict__ W,
    const float* __restrict__ b, float* __restrict__ xout, int n, int base) {
  __shared__ float st[256 * PADW];
  int tid = threadIdx.x;
  int node0 = blockIdx.x * 256;
  int node = node0 + tid;
  bool active = node < n;
  int rows = min(256, n - node0);
  float acc[HDIM];
  if (active) {
    float4 row[K / 4];
    const float4* xv = (const float4*)(xin + (size_t)node * K);
#pragma unroll
    for (int i = 0; i < K / 4; ++i) row[i] = xv[i];
#pragma unroll
    for (int f = 0; f < HDIM; ++f) acc[f] = b[f];  // uniform -> s_load
#pragma unroll
    for (int k4 = 0; k4 < K / 4; ++k4) {
#pragma unroll
      for (int j = 0; j < 4; ++j) {
        float xs = elem4(row[k4], j);
        int k = k4 * 4 + j;
#pragma unroll
        for (int f = 0; f < HDIM; ++f) acc[f] += xs * W[k * HDIM + f];
      }
    }
  }
  store_rows_coalesced(xout + (size_t)base * HDIM, st, acc, node0, rows, tid, active);
}

// ---------------- coarse histogram: LDS-aggregated, 293 bins ----------------
__global__ __launch_bounds__(256) void coarse_hist_kernel(const int* __restrict__ dst,
                                                          int* __restrict__ chist, int e) {
  __shared__ int h[NCB];
  int tid = threadIdx.x;
  int start = blockIdx.x * CHUNK;
  int len = min(CHUNK, e - start);
  for (int i = tid; i < NCB; i += 256) h[i] = 0;
  __syncthreads();
  for (int i = tid; i < len; i += 256) atomicAdd(&h[dst[start + i] >> 10], 1);
  __syncthreads();
  for (int b = tid; b < NCB; b += 256) {
    int c = h[b];
    if (c > 0) atomicAdd(&chist[b], c);
  }
}

// ---------------- exclusive scan of 293 coarse counts ----------------
__global__ __launch_bounds__(512) void coarse_scan_kernel(const int* __restrict__ chist,
                                                          int* __restrict__ cbase,
                                                          int* __restrict__ ccur) {
  __shared__ int sv[512];
  int t = threadIdx.x;
  sv[t] = (t < NCB) ? chist[t] : 0;
  __syncthreads();
  for (int o = 1; o < 512; o <<= 1) {
    int y = (t >= o) ? sv[t - o] : 0;
    __syncthreads();
    sv[t] += y;
    __syncthreads();
  }
  if (t < NCB) {
    int ex = (t == 0) ? 0 : sv[t - 1];
    cbase[t] = ex;
    ccur[t] = ex;
  }
}

// ---------------- coarse scatter: block-aggregated reservation, dense runs ----------------
// packed word = (src << 10) | (dst & 1023); src < 2^19 -> 29 bits.
__global__ __launch_bounds__(256) void coarse_scatter_kernel(
    const int* __restrict__ src, const int* __restrict__ dst,
    int* __restrict__ ccur, unsigned* __restrict__ packed, int e) {
  __shared__ int h[NCB];
  __shared__ int lbase[NCB];
  int tid = threadIdx.x;
  int start = blockIdx.x * CHUNK;
  int len = min(CHUNK, e - start);
  for (int i = tid; i < NCB; i += 256) h[i] = 0;
  __syncthreads();
  for (int i = tid; i < len; i += 256) atomicAdd(&h[dst[start + i] >> 10], 1);
  __syncthreads();
  for (int b = tid; b < NCB; b += 256) {
    int c = h[b];
    lbase[b] = (c > 0) ? atomicAdd(&ccur[b], c) : 0;  // reserve contiguous run
  }
  __syncthreads();
  for (int i = tid; i < NCB; i += 256) h[i] = 0;  // reuse as rank counters
  __syncthreads();
  for (int i = tid; i < len; i += 256) {
    int d = dst[start + i];
    int s = src[start + i];
    int b = d >> 10;
    int r = atomicAdd(&h[b], 1);
    packed[lbase[b] + r] = ((unsigned)s << 10) | (unsigned)(d & 1023);
  }
}

// ---------------- per-coarse-bucket counting sort -> node-grouped CSR ----------------
__global__ __launch_bounds__(256) void sort_coarse_kernel(
    const unsigned* __restrict__ packed, const int* __restrict__ cbase,
    const int* __restrict__ chist, int* __restrict__ eidx,
    int* __restrict__ nodeoff, int* __restrict__ deg) {
  __shared__ int cnts[1024];
  __shared__ int cur[1024];
  __shared__ int part[256];
  int cb = blockIdx.x;
  int tid = threadIdx.x;
  for (int i = tid; i < 1024; i += 256) cnts[i] = 0;
  __syncthreads();
  int base = cbase[cb];
  int cnt = chist[cb];
  for (int i = tid; i < cnt; i += 256)
    atomicAdd(&cnts[packed[base + i] & 1023u], 1);
  __syncthreads();
  int c0 = cnts[4 * tid + 0], c1 = cnts[4 * tid + 1];
  int c2 = cnts[4 * tid + 2], c3 = cnts[4 * tid + 3];
  part[tid] = c0 + c1 + c2 + c3;
  __syncthreads();
  for (int o = 1; o < 256; o <<= 1) {
    int y = (tid >= o) ? part[tid - o] : 0;
    __syncthreads();
    part[tid] += y;
    __syncthreads();
  }
  int pre = (tid == 0) ? 0 : part[tid - 1];
  int e0 = pre, e1 = e0 + c0, e2 = e1 + c1, e3 = e2 + c2;
  cur[4 * tid + 0] = e0; cur[4 * tid + 1] = e1;
  cur[4 * tid + 2] = e2; cur[4 * tid + 3] = e3;
  int nodebase = (cb << 10) + 4 * tid;
  if (nodebase + 0 < NTOT) { deg[nodebase + 0] = c0; nodeoff[nodebase + 0] = base + e0; }
  if (nodebase + 1 < NTOT) { deg[nodebase + 1] = c1; nodeoff[nodebase + 1] = base + e1; }
  if (nodebase + 2 < NTOT) { deg[nodebase + 2] = c2; nodeoff[nodebase + 2] = base + e2; }
  if (nodebase + 3 < NTOT) { deg[nodebase + 3] = c3; nodeoff[nodebase + 3] = base + e3; }
  __syncthreads();
  for (int i = tid; i < cnt; i += 256) {
    unsigned pr = packed[base + i];
    int dl = (int)(pr & 1023u);
    int r = atomicAdd(&cur[dl], 1);
    eidx[base + r] = (int)(pr >> 10);  // 64 KB region exclusive to this block
  }
}

// ---------------- mean aggregation: 16 lanes per node, float4 per lane ----------------
__global__ __launch_bounds__(256) void aggregate_kernel(
    const float* __restrict__ x, const int* __restrict__ off, const int* __restrict__ deg,
    const int* __restrict__ eidx, float* __restrict__ mean, int n) {
  int tid = blockIdx.x * 256 + threadIdx.x;
  int node = tid >> 4;
  int lane = tid & 15;
  if (node >= n) return;
  int start = off[node];
  int d = deg[node];
  float4 acc = make_float4(0.f, 0.f, 0.f, 0.f);
  const float4* xv = (const float4*)x;
  for (int i = 0; i < d; ++i) {
    int s = eidx[start + i];
    float4 v = xv[(size_t)s * 16 + lane];
    acc.x += v.x; acc.y += v.y; acc.z += v.z; acc.w += v.w;
  }
  float inv = 1.0f / (float)(d > 0 ? d : 1);
  acc.x *= inv; acc.y *= inv; acc.z *= inv; acc.w *= inv;
  ((float4*)mean)[(size_t)node * 16 + lane] = acc;
}

// ---------------- combine: out = relu(mean@Wl + x@Wr + b) ----------------
__global__ __launch_bounds__(256, 2) void combine_kernel(
    const float* __restrict__ mean, const float* __restrict__ x,
    const float* __restrict__ Wl, const float* __restrict__ Wr,
    const float* __restrict__ bb, float* __restrict__ out, int n) {
  __shared__ float st[256 * PADW];
  int tid = threadIdx.x;
  int node0 = blockIdx.x * 256;
  int node = node0 + tid;
  bool active = node < n;
  int rows = min(256, n - node0);
  float acc[HDIM];
  if (active) {
#pragma unroll
    for (int f = 0; f < HDIM; ++f) acc[f] = bb[f];
    float4 row[16];
    // phase 1: mean @ Wl  (burst-load full row, then FMA from registers)
    const float4* mv = (const float4*)(mean + (size_t)node * HDIM);
#pragma unroll
    for (int i = 0; i < 16; ++i) row[i] = mv[i];
#pragma unroll
    for (int k4 = 0; k4 < 16; ++k4) {
#pragma unroll
      for (int j = 0; j < 4; ++j) {
        float ms = elem4(row[k4], j);
        int k = k4 * 4 + j;
#pragma unroll
        for (int f = 0; f < HDIM; ++f) acc[f] += ms * Wl[k * HDIM + f];
      }
    }
    // phase 2: x @ Wr
    const float4* xv = (const float4*)(x + (size_t)node * HDIM);
#pragma unroll
    for (int i = 0; i < 16; ++i) row[i] = xv[i];
#pragma unroll
    for (int k4 = 0; k4 < 16; ++k4) {
#pragma unroll
      for (int j = 0; j < 4; ++j) {
        float xs = elem4(row[k4], j);
        int k = k4 * 4 + j;
#pragma unroll
        for (int f = 0; f < HDIM; ++f) acc[f] += xs * Wr[k * HDIM + f];
      }
    }
#pragma unroll
    for (int f = 0; f < HDIM; ++f) acc[f] = fmaxf(acc[f], 0.f);
  }
  store_rows_coalesced(out, st, acc, node0, rows, tid, active);
}

// ---------------- classifier: out = relu(x@Wc1+bc1)@Wc2 + bc2 ----------------
__global__ __launch_bounds__(256, 2) void classifier_kernel(
    const float* __restrict__ x, const float* __restrict__ W1, const float* __restrict__ b1,
    const float* __restrict__ W2, const float* __restrict__ b2,
    float* __restrict__ out, int n) {
  int node = blockIdx.x * 256 + threadIdx.x;
  if (node >= n) return;
  float4 row[16];
  const float4* xv = (const float4*)(x + (size_t)node * HDIM);
#pragma unroll
  for (int i = 0; i < 16; ++i) row[i] = xv[i];
  float h[32];
#pragma unroll
  for (int f = 0; f < 32; ++f) h[f] = b1[f];
#pragma unroll
  for (int k4 = 0; k4 < 16; ++k4) {
#pragma unroll
    for (int j = 0; j < 4; ++j) {
      float xs = elem4(row[k4], j);
      int k = k4 * 4 + j;
#pragma unroll
      for (int f = 0; f < 32; ++f) h[f] += xs * W1[k * 32 + f];
    }
  }
  float o0 = b2[0], o1 = b2[1];
#pragma unroll
  for (int f = 0; f < 32; ++f) {
    float hv = fmaxf(h[f], 0.f);
    o0 += hv * W2[f * 2 + 0];
    o1 += hv * W2[f * 2 + 1];
  }
  float2 o;
  o.x = o0; o.y = o1;
  *(float2*)(out + (size_t)node * 2) = o;   // lane-consecutive: already coalesced
}

extern "C" void kernel_launch(void* const* d_in, const int* in_sizes, int n_in,
                              void* d_out, int out_size, void* d_ws, size_t ws_size,
                              hipStream_t stream) {
  const float* x_ind = (const float*)d_in[0];
  const float* x_com = (const float*)d_in[1];
  const float* x_tru = (const float*)d_in[2];
  const int*   ei    = (const int*)d_in[3];
  const float* W_ind = (const float*)d_in[4];
  const float* b_ind = (const float*)d_in[5];
  const float* W_com = (const float*)d_in[6];
  const float* b_com = (const float*)d_in[7];
  const float* W_tru = (const float*)d_in[8];
  const float* b_tru = (const float*)d_in[9];
  const float* W1l = (const float*)d_in[10];
  const float* W1r = (const float*)d_in[11];
  const float* b1  = (const float*)d_in[12];
  const float* W2l = (const float*)d_in[13];
  const float* W2r = (const float*)d_in[14];
  const float* b2  = (const float*)d_in[15];
  const float* Wc1 = (const float*)d_in[16];
  const float* bc1 = (const float*)d_in[17];
  const float* Wc2 = (const float*)d_in[18];
  const float* bc2 = (const float*)d_in[19];

  const int* srcp = ei;           // edge_index[0]
  const int* dstp = ei + NEDGE;   // edge_index[1]

  // workspace layout (~252 MB)
  size_t fcount = (size_t)NTOT * HDIM;  // 19.2M floats per buffer
  float* x0 = (float*)d_ws;
  float* x1 = x0 + fcount;
  float* mn = x1 + fcount;
  unsigned* packed = (unsigned*)mn;      // ALIAS: packed dead before mn first written
  int* eidx    = (int*)(mn + fcount);
  int* nodeoff = eidx + NEDGE;
  int* deg     = nodeoff + NTOT;
  int* chist   = deg + NTOT;
  int* cbase   = chist + NCB;
  int* ccur    = cbase + NCB;
  size_t needed = (3 * fcount + (size_t)NEDGE + 2 * (size_t)NTOT + 3 * (size_t)NCB) * 4;
  if (ws_size < needed) return;  // would corrupt; fail visibly instead

  hipMemsetAsync(chist, 0, (size_t)NCB * sizeof(int), stream);

  // encoders (write x0; independent of edge pipeline)
  encode_kernel<32><<<(N_IND + 255) / 256, 256, 0, stream>>>(x_ind, W_ind, b_ind, x0, N_IND, 0);
  encode_kernel<48><<<(N_COM + 255) / 256, 256, 0, stream>>>(x_com, W_com, b_com, x0, N_COM, N_IND);
  encode_kernel<24><<<(N_TRU + 255) / 256, 256, 0, stream>>>(x_tru, W_tru, b_tru, x0, N_TRU, N_IND + N_COM);

  // coarse partition -> per-coarse-bucket counting sort -> node-grouped CSR
  coarse_hist_kernel<<<NCHUNKS, 256, 0, stream>>>(dstp, chist, NEDGE);
  coarse_scan_kernel<<<1, 512, 0, stream>>>(chist, cbase, ccur);
  coarse_scatter_kernel<<<NCHUNKS, 256, 0, stream>>>(srcp, dstp, ccur, packed, NEDGE);
  sort_coarse_kernel<<<NCB, 256, 0, stream>>>(packed, cbase, chist, eidx, nodeoff, deg);

  // SAGE layer 1
  aggregate_kernel<<<(NTOT * 16 + 255) / 256, 256, 0, stream>>>(x0, nodeoff, deg, eidx, mn, NTOT);
  combine_kernel<<<(NTOT + 255) / 256, 256, 0, stream>>>(mn, x0, W1l, W1r, b1, x1, NTOT);

  // SAGE layer 2
  aggregate_kernel<<<(NTOT * 16 + 255) / 256, 256, 0, stream>>>(x1, nodeoff, deg, eidx, mn, NTOT);
  combine_kernel<<<(NTOT + 255) / 256, 256, 0, stream>>>(mn, x1, W2l, W2r, b2, x0, NTOT);

  // classifier
  classifier_kernel<<<(NTOT + 255) / 256, 256, 0, stream>>>(x0, Wc1, bc1, Wc2, bc2,
                                                            (float*)d_out, NTOT);
}

// Round 7
// 1068.345 us; speedup vs baseline: 4.0896x; 1.0157x over previous
//
#include <hip/hip_runtime.h>

#define N_IND 100000
#define N_COM 100000
#define N_TRU 100000
#define NTOT  300000
#define NEDGE 4800000
#define HDIM  64
#define CHUNK 8192
#define NCHUNKS 586   // ceil(NEDGE/CHUNK)
#define NCB 293       // ceil(NTOT/1024) coarse buckets of 1024 nodes
#define PADW 33       // 32 cols + 1 pad: copy-in/out <=2-way bank alias (free)

typedef float v4f __attribute__((ext_vector_type(4)));

static __device__ __forceinline__ float elem4(const float4 v, int j) {
  return j == 0 ? v.x : j == 1 ? v.y : j == 2 ? v.z : v.w;
}

// Coalesced epilogue: stage acc[64] rows through LDS in 2 x 32-col stages so
// every global store instruction writes full 64B lines (fixes 4x write amp).
static __device__ __forceinline__ void store_rows_coalesced(
    float* __restrict__ out, float* __restrict__ st, const float* acc,
    int node0, int rows, int tid, bool active) {
#pragma unroll
  for (int stage = 0; stage < 2; ++stage) {
    __syncthreads();  // protect LDS reuse across stages
    if (active) {
#pragma unroll
      for (int j = 0; j < 32; ++j) st[tid * PADW + j] = acc[stage * 32 + j];
    }
    __syncthreads();
#pragma unroll
    for (int it = 0; it < 8; ++it) {
      int e = it * 256 + tid;   // float4 index within the 256x32 tile
      int r = e >> 3;
      int c = (e & 7) * 4;
      if (r < rows) {
        float4 o;
        o.x = st[r * PADW + c + 0];
        o.y = st[r * PADW + c + 1];
        o.z = st[r * PADW + c + 2];
        o.w = st[r * PADW + c + 3];
        *(float4*)(out + (size_t)(node0 + r) * HDIM + stage * 32 + c) = o;
      }
    }
  }
}

// ---------------- encoder: out[base+n] = x[n] @ W + b ----------------
template <int K>
__global__ __launch_bounds__(256, 2) void encode_kernel(
    const float* __restrict__ xin, const float* __restrict__ W,
    const float* __restrict__ b, float* __restrict__ xout, int n, int base) {
  __shared__ float st[256 * PADW];
  int tid = threadIdx.x;
  int node0 = blockIdx.x * 256;
  int node = node0 + tid;
  bool active = node < n;
  int rows = min(256, n - node0);
  float acc[HDIM];
  if (active) {
    float4 row[K / 4];
    const float4* xv = (const float4*)(xin + (size_t)node * K);
#pragma unroll
    for (int i = 0; i < K / 4; ++i) row[i] = xv[i];
#pragma unroll
    for (int f = 0; f < HDIM; ++f) acc[f] = b[f];  // uniform -> s_load
#pragma unroll
    for (int k4 = 0; k4 < K / 4; ++k4) {
#pragma unroll
      for (int j = 0; j < 4; ++j) {
        float xs = elem4(row[k4], j);
        int k = k4 * 4 + j;
#pragma unroll
        for (int f = 0; f < HDIM; ++f) acc[f] += xs * W[k * HDIM + f];
      }
    }
  }
  store_rows_coalesced(xout + (size_t)base * HDIM, st, acc, node0, rows, tid, active);
}

// ---------------- coarse histogram: LDS-aggregated, 293 bins ----------------
__global__ __launch_bounds__(256) void coarse_hist_kernel(const int* __restrict__ dst,
                                                          int* __restrict__ chist, int e) {
  __shared__ int h[NCB];
  int tid = threadIdx.x;
  int start = blockIdx.x * CHUNK;
  int len = min(CHUNK, e - start);
  for (int i = tid; i < NCB; i += 256) h[i] = 0;
  __syncthreads();
  for (int i = tid; i < len; i += 256) atomicAdd(&h[dst[start + i] >> 10], 1);
  __syncthreads();
  for (int b = tid; b < NCB; b += 256) {
    int c = h[b];
    if (c > 0) atomicAdd(&chist[b], c);
  }
}

// ---------------- exclusive scan of 293 coarse counts ----------------
__global__ __launch_bounds__(512) void coarse_scan_kernel(const int* __restrict__ chist,
                                                          int* __restrict__ cbase,
                                                          int* __restrict__ ccur) {
  __shared__ int sv[512];
  int t = threadIdx.x;
  sv[t] = (t < NCB) ? chist[t] : 0;
  __syncthreads();
  for (int o = 1; o < 512; o <<= 1) {
    int y = (t >= o) ? sv[t - o] : 0;
    __syncthreads();
    sv[t] += y;
    __syncthreads();
  }
  if (t < NCB) {
    int ex = (t == 0) ? 0 : sv[t - 1];
    cbase[t] = ex;
    ccur[t] = ex;
  }
}

// ---------------- coarse scatter: block-aggregated reservation, dense runs ----------------
// packed word = (src << 10) | (dst & 1023); src < 2^19 -> 29 bits.
__global__ __launch_bounds__(256) void coarse_scatter_kernel(
    const int* __restrict__ src, const int* __restrict__ dst,
    int* __restrict__ ccur, unsigned* __restrict__ packed, int e) {
  __shared__ int h[NCB];
  __shared__ int lbase[NCB];
  int tid = threadIdx.x;
  int start = blockIdx.x * CHUNK;
  int len = min(CHUNK, e - start);
  for (int i = tid; i < NCB; i += 256) h[i] = 0;
  __syncthreads();
  for (int i = tid; i < len; i += 256) atomicAdd(&h[dst[start + i] >> 10], 1);
  __syncthreads();
  for (int b = tid; b < NCB; b += 256) {
    int c = h[b];
    lbase[b] = (c > 0) ? atomicAdd(&ccur[b], c) : 0;  // reserve contiguous run
  }
  __syncthreads();
  for (int i = tid; i < NCB; i += 256) h[i] = 0;  // reuse as rank counters
  __syncthreads();
  for (int i = tid; i < len; i += 256) {
    int d = dst[start + i];
    int s = src[start + i];
    int b = d >> 10;
    int r = atomicAdd(&h[b], 1);
    packed[lbase[b] + r] = ((unsigned)s << 10) | (unsigned)(d & 1023);
  }
}

// ---------------- per-coarse-bucket counting sort -> node-grouped CSR ----------------
__global__ __launch_bounds__(256) void sort_coarse_kernel(
    const unsigned* __restrict__ packed, const int* __restrict__ cbase,
    const int* __restrict__ chist, int* __restrict__ eidx,
    int* __restrict__ nodeoff, int* __restrict__ deg) {
  __shared__ int cnts[1024];
  __shared__ int cur[1024];
  __shared__ int part[256];
  int cb = blockIdx.x;
  int tid = threadIdx.x;
  for (int i = tid; i < 1024; i += 256) cnts[i] = 0;
  __syncthreads();
  int base = cbase[cb];
  int cnt = chist[cb];
  for (int i = tid; i < cnt; i += 256)
    atomicAdd(&cnts[packed[base + i] & 1023u], 1);
  __syncthreads();
  int c0 = cnts[4 * tid + 0], c1 = cnts[4 * tid + 1];
  int c2 = cnts[4 * tid + 2], c3 = cnts[4 * tid + 3];
  part[tid] = c0 + c1 + c2 + c3;
  __syncthreads();
  for (int o = 1; o < 256; o <<= 1) {
    int y = (tid >= o) ? part[tid - o] : 0;
    __syncthreads();
    part[tid] += y;
    __syncthreads();
  }
  int pre = (tid == 0) ? 0 : part[tid - 1];
  int e0 = pre, e1 = e0 + c0, e2 = e1 + c1, e3 = e2 + c2;
  cur[4 * tid + 0] = e0; cur[4 * tid + 1] = e1;
  cur[4 * tid + 2] = e2; cur[4 * tid + 3] = e3;
  int nodebase = (cb << 10) + 4 * tid;
  if (nodebase + 0 < NTOT) { deg[nodebase + 0] = c0; nodeoff[nodebase + 0] = base + e0; }
  if (nodebase + 1 < NTOT) { deg[nodebase + 1] = c1; nodeoff[nodebase + 1] = base + e1; }
  if (nodebase + 2 < NTOT) { deg[nodebase + 2] = c2; nodeoff[nodebase + 2] = base + e2; }
  if (nodebase + 3 < NTOT) { deg[nodebase + 3] = c3; nodeoff[nodebase + 3] = base + e3; }
  __syncthreads();
  for (int i = tid; i < cnt; i += 256) {
    unsigned pr = packed[base + i];
    int dl = (int)(pr & 1023u);
    int r = atomicAdd(&cur[dl], 1);
    eidx[base + r] = (int)(pr >> 10);  // 64 KB region exclusive to this block
  }
}

// ---------------- mean aggregation: 16 lanes/node, unroll x4, nt streams ----------------
__global__ __launch_bounds__(256) void aggregate_kernel(
    const float* __restrict__ x, const int* __restrict__ off, const int* __restrict__ deg,
    const int* __restrict__ eidx, float* __restrict__ mean, int n) {
  int tid = blockIdx.x * 256 + threadIdx.x;
  int node = tid >> 4;
  int lane = tid & 15;
  if (node >= n) return;
  int start = off[node];
  int d = deg[node];
  const float4* xv = (const float4*)x;
  float4 a0 = make_float4(0.f, 0.f, 0.f, 0.f);
  float4 a1 = make_float4(0.f, 0.f, 0.f, 0.f);
  float4 a2 = make_float4(0.f, 0.f, 0.f, 0.f);
  float4 a3 = make_float4(0.f, 0.f, 0.f, 0.f);
  int i = 0;
  for (; i + 4 <= d; i += 4) {
    // batched nt index loads, then 4 independent gathers in flight
    int s0 = __builtin_nontemporal_load(eidx + start + i + 0);
    int s1 = __builtin_nontemporal_load(eidx + start + i + 1);
    int s2 = __builtin_nontemporal_load(eidx + start + i + 2);
    int s3 = __builtin_nontemporal_load(eidx + start + i + 3);
    float4 v0 = xv[(size_t)s0 * 16 + lane];
    float4 v1 = xv[(size_t)s1 * 16 + lane];
    float4 v2 = xv[(size_t)s2 * 16 + lane];
    float4 v3 = xv[(size_t)s3 * 16 + lane];
    a0.x += v0.x; a0.y += v0.y; a0.z += v0.z; a0.w += v0.w;
    a1.x += v1.x; a1.y += v1.y; a1.z += v1.z; a1.w += v1.w;
    a2.x += v2.x; a2.y += v2.y; a2.z += v2.z; a2.w += v2.w;
    a3.x += v3.x; a3.y += v3.y; a3.z += v3.z; a3.w += v3.w;
  }
  for (; i < d; ++i) {
    int s = __builtin_nontemporal_load(eidx + start + i);
    float4 v = xv[(size_t)s * 16 + lane];
    a0.x += v.x; a0.y += v.y; a0.z += v.z; a0.w += v.w;
  }
  float inv = 1.0f / (float)(d > 0 ? d : 1);
  v4f o;
  o[0] = (a0.x + a1.x + a2.x + a3.x) * inv;
  o[1] = (a0.y + a1.y + a2.y + a3.y) * inv;
  o[2] = (a0.z + a1.z + a2.z + a3.z) * inv;
  o[3] = (a0.w + a1.w + a2.w + a3.w) * inv;
  // mean is a pure stream (read once by combine): keep it out of L3
  __builtin_nontemporal_store(o, (v4f*)mean + (size_t)node * 16 + lane);
}

// ---------------- combine: out = relu(mean@Wl + x@Wr + b) ----------------
__global__ __launch_bounds__(256, 2) void combine_kernel(
    const float* __restrict__ mean, const float* __restrict__ x,
    const float* __restrict__ Wl, const float* __restrict__ Wr,
    const float* __restrict__ bb, float* __restrict__ out, int n) {
  __shared__ float st[256 * PADW];
  int tid = threadIdx.x;
  int node0 = blockIdx.x * 256;
  int node = node0 + tid;
  bool active = node < n;
  int rows = min(256, n - node0);
  float acc[HDIM];
  if (active) {
#pragma unroll
    for (int f = 0; f < HDIM; ++f) acc[f] = bb[f];
    // phase 1: mean @ Wl  (burst nt-load full row — stream, keep out of L3)
    v4f row[16];
    const v4f* mv = (const v4f*)mean + (size_t)node * 16;
#pragma unroll
    for (int i = 0; i < 16; ++i) row[i] = __builtin_nontemporal_load(mv + i);
#pragma unroll
    for (int k4 = 0; k4 < 16; ++k4) {
#pragma unroll
      for (int j = 0; j < 4; ++j) {
        float ms = row[k4][j];
        int k = k4 * 4 + j;
#pragma unroll
        for (int f = 0; f < HDIM; ++f) acc[f] += ms * Wl[k * HDIM + f];
      }
    }
    // phase 2: x @ Wr (temporal — x stays L3-resident for aggregate)
    const v4f* xv = (const v4f*)x + (size_t)node * 16;
#pragma unroll
    for (int i = 0; i < 16; ++i) row[i] = xv[i];
#pragma unroll
    for (int k4 = 0; k4 < 16; ++k4) {
#pragma unroll
      for (int j = 0; j < 4; ++j) {
        float xs = row[k4][j];
        int k = k4 * 4 + j;
#pragma unroll
        for (int f = 0; f < HDIM; ++f) acc[f] += xs * Wr[k * HDIM + f];
      }
    }
#pragma unroll
    for (int f = 0; f < HDIM; ++f) acc[f] = fmaxf(acc[f], 0.f);
  }
  store_rows_coalesced(out, st, acc, node0, rows, tid, active);
}

// ---------------- classifier: out = relu(x@Wc1+bc1)@Wc2 + bc2 ----------------
__global__ __launch_bounds__(256, 2) void classifier_kernel(
    const float* __restrict__ x, const float* __restrict__ W1, const float* __restrict__ b1,
    const float* __restrict__ W2, const float* __restrict__ b2,
    float* __restrict__ out, int n) {
  int node = blockIdx.x * 256 + threadIdx.x;
  if (node >= n) return;
  float4 row[16];
  const float4* xv = (const float4*)(x + (size_t)node * HDIM);
#pragma unroll
  for (int i = 0; i < 16; ++i) row[i] = xv[i];
  float h[32];
#pragma unroll
  for (int f = 0; f < 32; ++f) h[f] = b1[f];
#pragma unroll
  for (int k4 = 0; k4 < 16; ++k4) {
#pragma unroll
    for (int j = 0; j < 4; ++j) {
      float xs = elem4(row[k4], j);
      int k = k4 * 4 + j;
#pragma unroll
      for (int f = 0; f < 32; ++f) h[f] += xs * W1[k * 32 + f];
    }
  }
  float o0 = b2[0], o1 = b2[1];
#pragma unroll
  for (int f = 0; f < 32; ++f) {
    float hv = fmaxf(h[f], 0.f);
    o0 += hv * W2[f * 2 + 0];
    o1 += hv * W2[f * 2 + 1];
  }
  float2 o;
  o.x = o0; o.y = o1;
  *(float2*)(out + (size_t)node * 2) = o;   // lane-consecutive: already coalesced
}

extern "C" void kernel_launch(void* const* d_in, const int* in_sizes, int n_in,
                              void* d_out, int out_size, void* d_ws, size_t ws_size,
                              hipStream_t stream) {
  const float* x_ind = (const float*)d_in[0];
  const float* x_com = (const float*)d_in[1];
  const float* x_tru = (const float*)d_in[2];
  const int*   ei    = (const int*)d_in[3];
  const float* W_ind = (const float*)d_in[4];
  const float* b_ind = (const float*)d_in[5];
  const float* W_com = (const float*)d_in[6];
  const float* b_com = (const float*)d_in[7];
  const float* W_tru = (const float*)d_in[8];
  const float* b_tru = (const float*)d_in[9];
  const float* W1l = (const float*)d_in[10];
  const float* W1r = (const float*)d_in[11];
  const float* b1  = (const float*)d_in[12];
  const float* W2l = (const float*)d_in[13];
  const float* W2r = (const float*)d_in[14];
  const float* b2  = (const float*)d_in[15];
  const float* Wc1 = (const float*)d_in[16];
  const float* bc1 = (const float*)d_in[17];
  const float* Wc2 = (const float*)d_in[18];
  const float* bc2 = (const float*)d_in[19];

  const int* srcp = ei;           // edge_index[0]
  const int* dstp = ei + NEDGE;   // edge_index[1]

  // workspace layout (~252 MB)
  size_t fcount = (size_t)NTOT * HDIM;  // 19.2M floats per buffer
  float* x0 = (float*)d_ws;
  float* x1 = x0 + fcount;
  float* mn = x1 + fcount;
  unsigned* packed = (unsigned*)mn;      // ALIAS: packed dead before mn first written
  int* eidx    = (int*)(mn + fcount);
  int* nodeoff = eidx + NEDGE;
  int* deg     = nodeoff + NTOT;
  int* chist   = deg + NTOT;
  int* cbase   = chist + NCB;
  int* ccur    = cbase + NCB;
  size_t needed = (3 * fcount + (size_t)NEDGE + 2 * (size_t)NTOT + 3 * (size_t)NCB) * 4;
  if (ws_size < needed) return;  // would corrupt; fail visibly instead

  hipMemsetAsync(chist, 0, (size_t)NCB * sizeof(int), stream);

  // encoders (write x0; independent of edge pipeline)
  encode_kernel<32><<<(N_IND + 255) / 256, 256, 0, stream>>>(x_ind, W_ind, b_ind, x0, N_IND, 0);
  encode_kernel<48><<<(N_COM + 255) / 256, 256, 0, stream>>>(x_com, W_com, b_com, x0, N_COM, N_IND);
  encode_kernel<24><<<(N_TRU + 255) / 256, 256, 0, stream>>>(x_tru, W_tru, b_tru, x0, N_TRU, N_IND + N_COM);

  // coarse partition -> per-coarse-bucket counting sort -> node-grouped CSR
  coarse_hist_kernel<<<NCHUNKS, 256, 0, stream>>>(dstp, chist, NEDGE);
  coarse_scan_kernel<<<1, 512, 0, stream>>>(chist, cbase, ccur);
  coarse_scatter_kernel<<<NCHUNKS, 256, 0, stream>>>(srcp, dstp, ccur, packed, NEDGE);
  sort_coarse_kernel<<<NCB, 256, 0, stream>>>(packed, cbase, chist, eidx, nodeoff, deg);

  // SAGE layer 1
  aggregate_kernel<<<(NTOT * 16 + 255) / 256, 256, 0, stream>>>(x0, nodeoff, deg, eidx, mn, NTOT);
  combine_kernel<<<(NTOT + 255) / 256, 256, 0, stream>>>(mn, x0, W1l, W1r, b1, x1, NTOT);

  // SAGE layer 2
  aggregate_kernel<<<(NTOT * 16 + 255) / 256, 256, 0, stream>>>(x1, nodeoff, deg, eidx, mn, NTOT);
  combine_kernel<<<(NTOT + 255) / 256, 256, 0, stream>>>(mn, x1, W2l, W2r, b2, x0, NTOT);

  // classifier
  classifier_kernel<<<(NTOT + 255) / 256, 256, 0, stream>>>(x0, Wc1, bc1, Wc2, bc2,
                                                            (float*)d_out, NTOT);
}

// Round 8
// 907.944 us; speedup vs baseline: 4.8121x; 1.1767x over previous
//
#include <hip/hip_runtime.h>

#define N_IND 100000
#define N_COM 100000
#define N_TRU 100000
#define NTOT  300000
#define NEDGE 4800000
#define HDIM  64
#define CHUNK 8192
#define NCHUNKS 586   // ceil(NEDGE/CHUNK)
#define NCB 293       // ceil(NTOT/1024) coarse buckets of 1024 nodes
#define PADW 33       // 32 cols + 1 pad: copy-in/out <=2-way bank alias (free)

typedef float v4f __attribute__((ext_vector_type(4)));

static __device__ __forceinline__ float elem4(const float4 v, int j) {
  return j == 0 ? v.x : j == 1 ? v.y : j == 2 ? v.z : v.w;
}

// fp32 -> bf16 round-to-nearest-even
static __device__ __forceinline__ unsigned short f2bf(float f) {
  unsigned u = __float_as_uint(f);
  unsigned r = (u + 0x7FFFu + ((u >> 16) & 1u)) >> 16;
  return (unsigned short)r;
}
static __device__ __forceinline__ float bf2f(unsigned short h) {
  return __uint_as_float(((unsigned)h) << 16);
}

// Coalesced fp32 epilogue via LDS (full 64B lines per store instruction).
static __device__ __forceinline__ void store_rows_f32(
    float* __restrict__ out, float* __restrict__ st, const float* acc,
    int node0, int rows, int tid, bool active) {
#pragma unroll
  for (int stage = 0; stage < 2; ++stage) {
    __syncthreads();
    if (active) {
#pragma unroll
      for (int j = 0; j < 32; ++j) st[tid * PADW + j] = acc[stage * 32 + j];
    }
    __syncthreads();
#pragma unroll
    for (int it = 0; it < 8; ++it) {
      int e = it * 256 + tid;
      int r = e >> 3;
      int c = (e & 7) * 4;
      if (r < rows) {
        float4 o;
        o.x = st[r * PADW + c + 0];
        o.y = st[r * PADW + c + 1];
        o.z = st[r * PADW + c + 2];
        o.w = st[r * PADW + c + 3];
        *(float4*)(out + (size_t)(node0 + r) * HDIM + stage * 32 + c) = o;
      }
    }
  }
}

// Coalesced bf16 epilogue: 8-lane groups write 64B line-complete ushort4 runs.
static __device__ __forceinline__ void store_rows_bf16(
    unsigned short* __restrict__ out, float* __restrict__ st, const float* acc,
    int node0, int rows, int tid, bool active) {
#pragma unroll
  for (int stage = 0; stage < 2; ++stage) {
    __syncthreads();
    if (active) {
#pragma unroll
      for (int j = 0; j < 32; ++j) st[tid * PADW + j] = acc[stage * 32 + j];
    }
    __syncthreads();
#pragma unroll
    for (int it = 0; it < 8; ++it) {
      int e = it * 256 + tid;
      int r = e >> 3;
      int c = (e & 7) * 4;
      if (r < rows) {
        ushort4 o;
        o.x = f2bf(st[r * PADW + c + 0]);
        o.y = f2bf(st[r * PADW + c + 1]);
        o.z = f2bf(st[r * PADW + c + 2]);
        o.w = f2bf(st[r * PADW + c + 3]);
        *(ushort4*)(out + (size_t)(node0 + r) * HDIM + stage * 32 + c) = o;
      }
    }
  }
}

// ---------------- encoder: xb[base+n] = bf16(x[n] @ W + b) ----------------
template <int K>
__global__ __launch_bounds__(256, 2) void encode_kernel(
    const float* __restrict__ xin, const float* __restrict__ W,
    const float* __restrict__ b, unsigned short* __restrict__ xbout, int n, int base) {
  __shared__ float st[256 * PADW];
  int tid = threadIdx.x;
  int node0 = blockIdx.x * 256;
  int node = node0 + tid;
  bool active = node < n;
  int rows = min(256, n - node0);
  float acc[HDIM];
  if (active) {
    float4 row[K / 4];
    const float4* xv = (const float4*)(xin + (size_t)node * K);
#pragma unroll
    for (int i = 0; i < K / 4; ++i) row[i] = xv[i];
#pragma unroll
    for (int f = 0; f < HDIM; ++f) acc[f] = b[f];  // uniform -> s_load
#pragma unroll
    for (int k4 = 0; k4 < K / 4; ++k4) {
#pragma unroll
      for (int j = 0; j < 4; ++j) {
        float xs = elem4(row[k4], j);
        int k = k4 * 4 + j;
#pragma unroll
        for (int f = 0; f < HDIM; ++f) acc[f] += xs * W[k * HDIM + f];
      }
    }
  }
  store_rows_bf16(xbout + (size_t)base * HDIM, st, acc, node0, rows, tid, active);
}

// ---------------- coarse histogram: LDS-aggregated, 293 bins ----------------
__global__ __launch_bounds__(256) void coarse_hist_kernel(const int* __restrict__ dst,
                                                          int* __restrict__ chist, int e) {
  __shared__ int h[NCB];
  int tid = threadIdx.x;
  int start = blockIdx.x * CHUNK;
  int len = min(CHUNK, e - start);
  for (int i = tid; i < NCB; i += 256) h[i] = 0;
  __syncthreads();
  for (int i = tid; i < len; i += 256) atomicAdd(&h[dst[start + i] >> 10], 1);
  __syncthreads();
  for (int b = tid; b < NCB; b += 256) {
    int c = h[b];
    if (c > 0) atomicAdd(&chist[b], c);
  }
}

// ---------------- exclusive scan of 293 coarse counts ----------------
__global__ __launch_bounds__(512) void coarse_scan_kernel(const int* __restrict__ chist,
                                                          int* __restrict__ cbase,
                                                          int* __restrict__ ccur) {
  __shared__ int sv[512];
  int t = threadIdx.x;
  sv[t] = (t < NCB) ? chist[t] : 0;
  __syncthreads();
  for (int o = 1; o < 512; o <<= 1) {
    int y = (t >= o) ? sv[t - o] : 0;
    __syncthreads();
    sv[t] += y;
    __syncthreads();
  }
  if (t < NCB) {
    int ex = (t == 0) ? 0 : sv[t - 1];
    cbase[t] = ex;
    ccur[t] = ex;
  }
}

// ---------------- coarse scatter: block-aggregated reservation, dense runs ----------------
// packed word = (src << 10) | (dst & 1023); src < 2^19 -> 29 bits.
__global__ __launch_bounds__(256) void coarse_scatter_kernel(
    const int* __restrict__ src, const int* __restrict__ dst,
    int* __restrict__ ccur, unsigned* __restrict__ packed, int e) {
  __shared__ int h[NCB];
  __shared__ int lbase[NCB];
  int tid = threadIdx.x;
  int start = blockIdx.x * CHUNK;
  int len = min(CHUNK, e - start);
  for (int i = tid; i < NCB; i += 256) h[i] = 0;
  __syncthreads();
  for (int i = tid; i < len; i += 256) atomicAdd(&h[dst[start + i] >> 10], 1);
  __syncthreads();
  for (int b = tid; b < NCB; b += 256) {
    int c = h[b];
    lbase[b] = (c > 0) ? atomicAdd(&ccur[b], c) : 0;  // reserve contiguous run
  }
  __syncthreads();
  for (int i = tid; i < NCB; i += 256) h[i] = 0;  // reuse as rank counters
  __syncthreads();
  for (int i = tid; i < len; i += 256) {
    int d = dst[start + i];
    int s = src[start + i];
    int b = d >> 10;
    int r = atomicAdd(&h[b], 1);
    packed[lbase[b] + r] = ((unsigned)s << 10) | (unsigned)(d & 1023);
  }
}

// ---------------- per-coarse-bucket counting sort -> node-grouped CSR ----------------
__global__ __launch_bounds__(256) void sort_coarse_kernel(
    const unsigned* __restrict__ packed, const int* __restrict__ cbase,
    const int* __restrict__ chist, int* __restrict__ eidx,
    int* __restrict__ nodeoff, int* __restrict__ deg) {
  __shared__ int cnts[1024];
  __shared__ int cur[1024];
  __shared__ int part[256];
  int cb = blockIdx.x;
  int tid = threadIdx.x;
  for (int i = tid; i < 1024; i += 256) cnts[i] = 0;
  __syncthreads();
  int base = cbase[cb];
  int cnt = chist[cb];
  for (int i = tid; i < cnt; i += 256)
    atomicAdd(&cnts[packed[base + i] & 1023u], 1);
  __syncthreads();
  int c0 = cnts[4 * tid + 0], c1 = cnts[4 * tid + 1];
  int c2 = cnts[4 * tid + 2], c3 = cnts[4 * tid + 3];
  part[tid] = c0 + c1 + c2 + c3;
  __syncthreads();
  for (int o = 1; o < 256; o <<= 1) {
    int y = (tid >= o) ? part[tid - o] : 0;
    __syncthreads();
    part[tid] += y;
    __syncthreads();
  }
  int pre = (tid == 0) ? 0 : part[tid - 1];
  int e0 = pre, e1 = e0 + c0, e2 = e1 + c1, e3 = e2 + c2;
  cur[4 * tid + 0] = e0; cur[4 * tid + 1] = e1;
  cur[4 * tid + 2] = e2; cur[4 * tid + 3] = e3;
  int nodebase = (cb << 10) + 4 * tid;
  if (nodebase + 0 < NTOT) { deg[nodebase + 0] = c0; nodeoff[nodebase + 0] = base + e0; }
  if (nodebase + 1 < NTOT) { deg[nodebase + 1] = c1; nodeoff[nodebase + 1] = base + e1; }
  if (nodebase + 2 < NTOT) { deg[nodebase + 2] = c2; nodeoff[nodebase + 2] = base + e2; }
  if (nodebase + 3 < NTOT) { deg[nodebase + 3] = c3; nodeoff[nodebase + 3] = base + e3; }
  __syncthreads();
  for (int i = tid; i < cnt; i += 256) {
    unsigned pr = packed[base + i];
    int dl = (int)(pr & 1023u);
    int r = atomicAdd(&cur[dl], 1);
    eidx[base + r] = (int)(pr >> 10);  // 64 KB region exclusive to this block
  }
}

// ---------------- mean aggregation: bf16 rows, 16 lanes/node, unroll x4 ----------------
__global__ __launch_bounds__(256) void aggregate_kernel(
    const unsigned short* __restrict__ xb, const int* __restrict__ off,
    const int* __restrict__ deg, const int* __restrict__ eidx,
    float* __restrict__ mean, int n) {
  int tid = blockIdx.x * 256 + threadIdx.x;
  int node = tid >> 4;
  int lane = tid & 15;
  if (node >= n) return;
  int start = off[node];
  int d = deg[node];
  const ushort4* xv = (const ushort4*)xb;   // row = 16 x ushort4 (128 B)
  float4 a0 = make_float4(0.f, 0.f, 0.f, 0.f);
  float4 a1 = make_float4(0.f, 0.f, 0.f, 0.f);
  float4 a2 = make_float4(0.f, 0.f, 0.f, 0.f);
  float4 a3 = make_float4(0.f, 0.f, 0.f, 0.f);
  int i = 0;
  for (; i + 4 <= d; i += 4) {
    int s0 = eidx[start + i + 0];
    int s1 = eidx[start + i + 1];
    int s2 = eidx[start + i + 2];
    int s3 = eidx[start + i + 3];
    ushort4 v0 = xv[(size_t)s0 * 16 + lane];
    ushort4 v1 = xv[(size_t)s1 * 16 + lane];
    ushort4 v2 = xv[(size_t)s2 * 16 + lane];
    ushort4 v3 = xv[(size_t)s3 * 16 + lane];
    a0.x += bf2f(v0.x); a0.y += bf2f(v0.y); a0.z += bf2f(v0.z); a0.w += bf2f(v0.w);
    a1.x += bf2f(v1.x); a1.y += bf2f(v1.y); a1.z += bf2f(v1.z); a1.w += bf2f(v1.w);
    a2.x += bf2f(v2.x); a2.y += bf2f(v2.y); a2.z += bf2f(v2.z); a2.w += bf2f(v2.w);
    a3.x += bf2f(v3.x); a3.y += bf2f(v3.y); a3.z += bf2f(v3.z); a3.w += bf2f(v3.w);
  }
  for (; i < d; ++i) {
    int s = eidx[start + i];
    ushort4 v = xv[(size_t)s * 16 + lane];
    a0.x += bf2f(v.x); a0.y += bf2f(v.y); a0.z += bf2f(v.z); a0.w += bf2f(v.w);
  }
  float inv = 1.0f / (float)(d > 0 ? d : 1);
  v4f o;
  o[0] = (a0.x + a1.x + a2.x + a3.x) * inv;
  o[1] = (a0.y + a1.y + a2.y + a3.y) * inv;
  o[2] = (a0.z + a1.z + a2.z + a3.z) * inv;
  o[3] = (a0.w + a1.w + a2.w + a3.w) * inv;
  // mean is a pure stream (read once by combine): keep it out of L3
  __builtin_nontemporal_store(o, (v4f*)mean + (size_t)node * 16 + lane);
}

// ---------------- combine: relu(mean@Wl + x@Wr + b); out fp32 OR bf16 ----------------
__global__ __launch_bounds__(256, 2) void combine_kernel(
    const float* __restrict__ mean, const unsigned short* __restrict__ xb,
    const float* __restrict__ Wl, const float* __restrict__ Wr,
    const float* __restrict__ bb, float* __restrict__ outf,
    unsigned short* __restrict__ outb, int n) {
  __shared__ float st[256 * PADW];
  int tid = threadIdx.x;
  int node0 = blockIdx.x * 256;
  int node = node0 + tid;
  bool active = node < n;
  int rows = min(256, n - node0);
  float acc[HDIM];
  if (active) {
#pragma unroll
    for (int f = 0; f < HDIM; ++f) acc[f] = bb[f];
    // phase 1: mean @ Wl  (burst nt-load full fp32 row — stream)
    v4f row[16];
    const v4f* mv = (const v4f*)mean + (size_t)node * 16;
#pragma unroll
    for (int i = 0; i < 16; ++i) row[i] = __builtin_nontemporal_load(mv + i);
#pragma unroll
    for (int k4 = 0; k4 < 16; ++k4) {
#pragma unroll
      for (int j = 0; j < 4; ++j) {
        float ms = row[k4][j];
        int k = k4 * 4 + j;
#pragma unroll
        for (int f = 0; f < HDIM; ++f) acc[f] += ms * Wl[k * HDIM + f];
      }
    }
    // phase 2: x(bf16) @ Wr
    const ushort4* xv = (const ushort4*)(xb + (size_t)node * HDIM);
    ushort4 hrow[16];
#pragma unroll
    for (int i = 0; i < 16; ++i) hrow[i] = xv[i];
#pragma unroll
    for (int k4 = 0; k4 < 16; ++k4) {
      float xs4[4] = {bf2f(hrow[k4].x), bf2f(hrow[k4].y), bf2f(hrow[k4].z), bf2f(hrow[k4].w)};
#pragma unroll
      for (int j = 0; j < 4; ++j) {
        int k = k4 * 4 + j;
#pragma unroll
        for (int f = 0; f < HDIM; ++f) acc[f] += xs4[j] * Wr[k * HDIM + f];
      }
    }
#pragma unroll
    for (int f = 0; f < HDIM; ++f) acc[f] = fmaxf(acc[f], 0.f);
  }
  if (outb) store_rows_bf16(outb, st, acc, node0, rows, tid, active);
  else      store_rows_f32(outf, st, acc, node0, rows, tid, active);
}

// ---------------- classifier: out = relu(x@Wc1+bc1)@Wc2 + bc2  (fp32 input) ----------------
__global__ __launch_bounds__(256, 2) void classifier_kernel(
    const float* __restrict__ x, const float* __restrict__ W1, const float* __restrict__ b1,
    const float* __restrict__ W2, const float* __restrict__ b2,
    float* __restrict__ out, int n) {
  int node = blockIdx.x * 256 + threadIdx.x;
  if (node >= n) return;
  float4 row[16];
  const float4* xv = (const float4*)(x + (size_t)node * HDIM);
#pragma unroll
  for (int i = 0; i < 16; ++i) row[i] = xv[i];
  float h[32];
#pragma unroll
  for (int f = 0; f < 32; ++f) h[f] = b1[f];
#pragma unroll
  for (int k4 = 0; k4 < 16; ++k4) {
#pragma unroll
    for (int j = 0; j < 4; ++j) {
      float xs = elem4(row[k4], j);
      int k = k4 * 4 + j;
#pragma unroll
      for (int f = 0; f < 32; ++f) h[f] += xs * W1[k * 32 + f];
    }
  }
  float o0 = b2[0], o1 = b2[1];
#pragma unroll
  for (int f = 0; f < 32; ++f) {
    float hv = fmaxf(h[f], 0.f);
    o0 += hv * W2[f * 2 + 0];
    o1 += hv * W2[f * 2 + 1];
  }
  float2 o;
  o.x = o0; o.y = o1;
  *(float2*)(out + (size_t)node * 2) = o;   // lane-consecutive: already coalesced
}

extern "C" void kernel_launch(void* const* d_in, const int* in_sizes, int n_in,
                              void* d_out, int out_size, void* d_ws, size_t ws_size,
                              hipStream_t stream) {
  const float* x_ind = (const float*)d_in[0];
  const float* x_com = (const float*)d_in[1];
  const float* x_tru = (const float*)d_in[2];
  const int*   ei    = (const int*)d_in[3];
  const float* W_ind = (const float*)d_in[4];
  const float* b_ind = (const float*)d_in[5];
  const float* W_com = (const float*)d_in[6];
  const float* b_com = (const float*)d_in[7];
  const float* W_tru = (const float*)d_in[8];
  const float* b_tru = (const float*)d_in[9];
  const float* W1l = (const float*)d_in[10];
  const float* W1r = (const float*)d_in[11];
  const float* b1  = (const float*)d_in[12];
  const float* W2l = (const float*)d_in[13];
  const float* W2r = (const float*)d_in[14];
  const float* b2  = (const float*)d_in[15];
  const float* Wc1 = (const float*)d_in[16];
  const float* bc1 = (const float*)d_in[17];
  const float* Wc2 = (const float*)d_in[18];
  const float* bc2 = (const float*)d_in[19];

  const int* srcp = ei;           // edge_index[0]
  const int* dstp = ei + NEDGE;   // edge_index[1]

  // workspace layout (~176 MB; round-1 proved >=252 MB available)
  size_t fcount = (size_t)NTOT * HDIM;  // 19.2M elems per feature tensor
  float* mn = (float*)d_ws;                       // fp32 mean / final fp32 features
  unsigned* packed = (unsigned*)mn;               // ALIAS: dead before mn first written
  unsigned short* xb0 = (unsigned short*)(mn + fcount);   // bf16 features layer-0
  unsigned short* xb1 = xb0 + fcount;                     // bf16 features layer-1
  int* eidx    = (int*)(xb1 + fcount);
  int* nodeoff = eidx + NEDGE;
  int* deg     = nodeoff + NTOT;
  int* chist   = deg + NTOT;
  int* cbase   = chist + NCB;
  int* ccur    = cbase + NCB;
  size_t needed = (size_t)(cbase + NCB - (int*)d_ws) * 4 + 64;
  if (ws_size < needed) return;  // would corrupt; fail visibly instead

  hipMemsetAsync(chist, 0, (size_t)NCB * sizeof(int), stream);

  // encoders (write bf16 xb0; independent of edge pipeline)
  encode_kernel<32><<<(N_IND + 255) / 256, 256, 0, stream>>>(x_ind, W_ind, b_ind, xb0, N_IND, 0);
  encode_kernel<48><<<(N_COM + 255) / 256, 256, 0, stream>>>(x_com, W_com, b_com, xb0, N_COM, N_IND);
  encode_kernel<24><<<(N_TRU + 255) / 256, 256, 0, stream>>>(x_tru, W_tru, b_tru, xb0, N_TRU, N_IND + N_COM);

  // coarse partition -> per-coarse-bucket counting sort -> node-grouped CSR
  coarse_hist_kernel<<<NCHUNKS, 256, 0, stream>>>(dstp, chist, NEDGE);
  coarse_scan_kernel<<<1, 512, 0, stream>>>(chist, cbase, ccur);
  coarse_scatter_kernel<<<NCHUNKS, 256, 0, stream>>>(srcp, dstp, ccur, packed, NEDGE);
  sort_coarse_kernel<<<NCB, 256, 0, stream>>>(packed, cbase, chist, eidx, nodeoff, deg);

  // SAGE layer 1: aggregate bf16 -> fp32 mean; combine -> bf16 x1
  aggregate_kernel<<<(NTOT * 16 + 255) / 256, 256, 0, stream>>>(xb0, nodeoff, deg, eidx, mn, NTOT);
  combine_kernel<<<(NTOT + 255) / 256, 256, 0, stream>>>(mn, xb0, W1l, W1r, b1, nullptr, xb1, NTOT);

  // SAGE layer 2: aggregate bf16 -> fp32 mean; combine -> fp32 in-place into mn
  aggregate_kernel<<<(NTOT * 16 + 255) / 256, 256, 0, stream>>>(xb1, nodeoff, deg, eidx, mn, NTOT);
  combine_kernel<<<(NTOT + 255) / 256, 256, 0, stream>>>(mn, xb1, W2l, W2r, b2, mn, nullptr, NTOT);

  // classifier (fp32 input, unquantized)
  classifier_kernel<<<(NTOT + 255) / 256, 256, 0, stream>>>(mn, Wc1, bc1, Wc2, bc2,
                                                            (float*)d_out, NTOT);
}